// Round 4
// baseline (500.283 us; speedup 1.0000x reference)
//
#include <hip/hip_runtime.h>

typedef __bf16 bf16x8 __attribute__((ext_vector_type(8)));
typedef float  f32x4  __attribute__((ext_vector_type(4)));
typedef unsigned int u32x4 __attribute__((ext_vector_type(4)));
typedef unsigned short u16x8 __attribute__((ext_vector_type(8)));
typedef unsigned short u16x4 __attribute__((ext_vector_type(4)));
typedef short i16x4 __attribute__((ext_vector_type(4)));

__device__ __forceinline__ unsigned short f2bf(float f) {
    return __builtin_bit_cast(unsigned short, (__bf16)f);
}
__device__ __forceinline__ bf16x8 as_bf16x8(u32x4 v) {
    return __builtin_bit_cast(bf16x8, v);
}

#define AS1 __attribute__((address_space(1)))
#define AS3 __attribute__((address_space(3)))
__device__ __forceinline__ void gload_lds16(const void* g, void* l) {
    __builtin_amdgcn_global_load_lds((const AS1 void*)g, (AS3 void*)l, 16, 0, 0);
}

// Window-major permutation: m' groups the 4 members of each 2x2 spatial
// window consecutively. n = b*4096 + hh*64 + ww  ->  m' = (b*1024 +
// (hh>>1)*32 + (ww>>1))*4 + (hh&1)*2 + (ww&1).

// ---------------- prep: fused cast+permute+pool (one x read), weight transpose ----------------
__global__ __launch_bounds__(256) void k_prep(
        const float* __restrict__ x,
        const float* __restrict__ h_qkv_w, const float* __restrict__ l_q_w,
        const float* __restrict__ l_kv_w, const float* __restrict__ h_proj_w,
        const float* __restrict__ l_proj_w,
        unsigned short* __restrict__ xb, unsigned short* __restrict__ xpb,
        unsigned short* __restrict__ wcatT, unsigned short* __restrict__ lkvT,
        unsigned short* __restrict__ hprojT, unsigned short* __restrict__ lprojT) {
    int blk = blockIdx.x;
    if (blk < 2048) {
        // thread -> (window widx, 8-channel chunk c8). Reads the 4 window rows once:
        // emits 4 xb rows (m'-order: consecutive!) + 1 pooled xpb row. x read once, not twice.
        int t = blk * 256 + threadIdx.x;
        int widx = t >> 6, c8 = (t & 63) << 3;
        int b = widx >> 10, rem = widx & 1023;
        int h2 = rem >> 5, w2 = rem & 31;
        const float* base = x + ((size_t)(b << 12) + (h2 << 7) + (w2 << 1)) * 512 + c8;
        f32x4 acc0 = {}, acc1 = {};
        const int roff[4] = {0, 1, 64, 65};   // (dh,dw) = (0,0),(0,1),(1,0),(1,1)
#pragma unroll
        for (int j = 0; j < 4; j++) {
            const float* src = base + (size_t)roff[j] * 512;
            f32x4 v0 = *(const f32x4*)src;
            f32x4 v1 = *(const f32x4*)(src + 4);
            acc0 += v0; acc1 += v1;
            u16x8 o = { f2bf(v0[0]), f2bf(v0[1]), f2bf(v0[2]), f2bf(v0[3]),
                        f2bf(v1[0]), f2bf(v1[1]), f2bf(v1[2]), f2bf(v1[3]) };
            *(u16x8*)(xb + ((size_t)widx * 4 + j) * 512 + c8) = o;
        }
        acc0 *= 0.25f; acc1 *= 0.25f;
        u16x8 p = { f2bf(acc0[0]), f2bf(acc0[1]), f2bf(acc0[2]), f2bf(acc0[3]),
                    f2bf(acc1[0]), f2bf(acc1[1]), f2bf(acc1[2]), f2bf(acc1[3]) };
        *(u16x8*)(xpb + (size_t)widx * 512 + c8) = p;
    } else {
        // weights -> B^T bf16
        int i = (blk - 2048) * 256 + threadIdx.x;
        if (i < 262144) {
            int n = i >> 9, k = i & 511;
            float v = (n < 256) ? h_qkv_w[k * 256 + n] : l_q_w[k * 256 + (n - 256)];
            wcatT[i] = f2bf(v);
        } else if (i < 524288) {
            int j = i - 262144; int n = j >> 9, k = j & 511;
            lkvT[j] = f2bf(l_kv_w[k * 512 + n]);
        } else if (i < 589824) {
            int j = i - 524288; int n = j >> 8, k = j & 255;
            hprojT[j] = f2bf(h_proj_w[k * 256 + n]);
        } else {
            int j = i - 589824; int n = j >> 8, k = j & 255;
            lprojT[j] = f2bf(l_proj_w[k * 256 + n]);
        }
    }
}

// ---------------- shared GEMM core: 128x128 tile, BK=32 (m97 structure) ----------------
__device__ __forceinline__ void mm_core(
        const unsigned short* __restrict__ A, const unsigned short* __restrict__ Bt,
        size_t row0, int col0, int K,
        unsigned short* As, unsigned short* Bs, f32x4 (&acc)[4][4]) {
    const int tid = threadIdx.x;
    const int wave = tid >> 6, lane = tid & 63;
    const int m16 = lane & 15, quad = lane >> 4;
    const int wr = wave >> 1, wc = wave & 1;
    const int srow = lane >> 2;
    const int scol = (lane & 3) * 8;
    const unsigned short* Ap0 = A + (row0 + wave * 32 + srow) * (size_t)K + scol;
    const unsigned short* Ap1 = Ap0 + (size_t)16 * K;
    const unsigned short* Bp0 = Bt + (size_t)(col0 + wave * 32 + srow) * K + scol;
    const unsigned short* Bp1 = Bp0 + (size_t)16 * K;
    unsigned short* Al0 = As + wave * 1024;
    unsigned short* Al1 = As + wave * 1024 + 512;
    unsigned short* Bl0 = Bs + wave * 1024;
    unsigned short* Bl1 = Bs + wave * 1024 + 512;

    for (int k0 = 0; k0 < K; k0 += 32) {
        __syncthreads();
        gload_lds16(Ap0 + k0, Al0);
        gload_lds16(Ap1 + k0, Al1);
        gload_lds16(Bp0 + k0, Bl0);
        gload_lds16(Bp1 + k0, Bl1);
        __syncthreads();
        bf16x8 af[4], bfr[4];
#pragma unroll
        for (int mi = 0; mi < 4; mi++)
            af[mi] = as_bf16x8(*(const u32x4*)(As + (wr * 64 + mi * 16 + m16) * 32 + quad * 8));
#pragma unroll
        for (int ni = 0; ni < 4; ni++)
            bfr[ni] = as_bf16x8(*(const u32x4*)(Bs + (wc * 64 + ni * 16 + m16) * 32 + quad * 8));
#pragma unroll
        for (int mi = 0; mi < 4; mi++)
#pragma unroll
            for (int ni = 0; ni < 4; ni++)
                acc[mi][ni] = __builtin_amdgcn_mfma_f32_16x16x32_bf16(af[mi], bfr[ni], acc[mi][ni], 0, 0, 0);
    }
}

// ---------------- launch 2: gemm1 (x@[hqkv|lq] + fused hifi) and kv-gemm (+fused V^T) ----------------
__global__ __launch_bounds__(256, 2) void k_mm512(
        const unsigned short* __restrict__ xb, const unsigned short* __restrict__ xpb,
        const unsigned short* __restrict__ wcatT, const unsigned short* __restrict__ lkvT,
        unsigned short* __restrict__ dbuf, unsigned short* __restrict__ qbuf,
        unsigned short* __restrict__ kbuf, unsigned short* __restrict__ vT) {
    __shared__ __align__(16) unsigned short As[128 * 32];
    __shared__ __align__(16) unsigned short Bs[128 * 32];
    const int flat = blockIdx.x;
    const bool isg1 = flat < 1024;
    const unsigned short* A;
    const unsigned short* Bt;
    size_t row0; int col0;
    if (isg1) { A = xb;  Bt = wcatT; row0 = (size_t)(flat >> 2) * 128; col0 = (flat & 3) * 128; }
    else { int f = flat - 1024; A = xpb; Bt = lkvT; row0 = (size_t)(f >> 2) * 128; col0 = (f & 3) * 128; }

    f32x4 acc[4][4] = {};
    mm_core(A, Bt, row0, col0, 512, As, Bs, acc);

    const int tid = threadIdx.x;
    const int wave = tid >> 6, lane = tid & 63;
    const int m16 = lane & 15, quad = lane >> 4;
    const int wr = wave >> 1, wc = wave & 1;

    if (isg1) {
        if (col0 < 256) {
            // hifi: lane's 4 rows are one 2x2 window (m'-order) -> dbuf = mean - val
#pragma unroll
            for (int mi = 0; mi < 4; mi++)
#pragma unroll
                for (int ni = 0; ni < 4; ni++) {
                    const int col = col0 + wc * 64 + ni * 16 + m16;
                    const size_t mb = row0 + wr * 64 + mi * 16 + quad * 4;
                    float v0 = acc[mi][ni][0], v1 = acc[mi][ni][1];
                    float v2 = acc[mi][ni][2], v3 = acc[mi][ni][3];
                    float m = 0.25f * ((v0 + v1) + (v2 + v3));
                    dbuf[(mb + 0) * 256 + col] = f2bf(m - v0);
                    dbuf[(mb + 1) * 256 + col] = f2bf(m - v1);
                    dbuf[(mb + 2) * 256 + col] = f2bf(m - v2);
                    dbuf[(mb + 3) * 256 + col] = f2bf(m - v3);
                }
        } else {
            // Q: fold softmax scale (0.125) and log2(e) into Q so attn uses exp2 directly
#pragma unroll
            for (int mi = 0; mi < 4; mi++)
#pragma unroll
                for (int ni = 0; ni < 4; ni++) {
                    const int col = col0 - 256 + wc * 64 + ni * 16 + m16;
                    const size_t mb = row0 + wr * 64 + mi * 16 + quad * 4;
#pragma unroll
                    for (int r = 0; r < 4; r++)
                        qbuf[(mb + r) * 256 + col] = f2bf(acc[mi][ni][r] * 0.18033688f);
                }
        }
    } else {
        if (col0 < 256) {
#pragma unroll
            for (int mi = 0; mi < 4; mi++)
#pragma unroll
                for (int ni = 0; ni < 4; ni++) {
                    const int col = col0 + wc * 64 + ni * 16 + m16;
                    const size_t row = row0 + wr * 64 + mi * 16 + quad * 4;
#pragma unroll
                    for (int r = 0; r < 4; r++)
                        kbuf[(row + r) * 256 + col] = f2bf(acc[mi][ni][r]);
                }
        } else {
            // V stored transposed: vT[(b*4+h)*64 + d][kv], lane's 4 rows = 4 consecutive kv
#pragma unroll
            for (int mi = 0; mi < 4; mi++)
#pragma unroll
                for (int ni = 0; ni < 4; ni++) {
                    const int d = col0 - 256 + wc * 64 + ni * 16 + m16;
                    const int hh = d >> 6, dd = d & 63;
                    const size_t kvg = row0 + wr * 64 + mi * 16 + quad * 4;
                    const int b = (int)(kvg >> 10), kv = (int)(kvg & 1023);
                    u16x4 pk = { f2bf(acc[mi][ni][0]), f2bf(acc[mi][ni][1]),
                                 f2bf(acc[mi][ni][2]), f2bf(acc[mi][ni][3]) };
                    *(u16x4*)(vT + (((size_t)(b * 4 + hh) * 64 + dd) << 10) + kv) = pk;
                }
        }
    }
}

// ---------------- launch 4: both projection GEMMs, un-permuting epilogue ----------------
__global__ __launch_bounds__(256, 2) void k_mmproj(
        const unsigned short* __restrict__ dbuf, const unsigned short* __restrict__ aout,
        const unsigned short* __restrict__ hprojT, const unsigned short* __restrict__ lprojT,
        const float* __restrict__ h_proj_b, const float* __restrict__ l_proj_b,
        float* __restrict__ out) {
    __shared__ __align__(16) unsigned short As[128 * 32];
    __shared__ __align__(16) unsigned short Bs[128 * 32];
    const int flat = blockIdx.x;               // 0..1023
    const bool hi = flat < 512;
    const int f = flat & 511;
    const unsigned short* A  = hi ? dbuf : aout;
    const unsigned short* Bt = hi ? hprojT : lprojT;
    const float* bias = hi ? h_proj_b : l_proj_b;
    const int coloff = hi ? 0 : 256;
    const size_t row0 = (size_t)(f >> 1) * 128;
    const int col0 = (f & 1) * 128;

    f32x4 acc[4][4] = {};
    mm_core(A, Bt, row0, col0, 256, As, Bs, acc);

    const int tid = threadIdx.x;
    const int wave = tid >> 6, lane = tid & 63;
    const int m16 = lane & 15, quad = lane >> 4;
    const int wr = wave >> 1, wc = wave & 1;

#pragma unroll
    for (int mi = 0; mi < 4; mi++)
#pragma unroll
        for (int ni = 0; ni < 4; ni++) {
            const int col = col0 + wc * 64 + ni * 16 + m16;
            const float bv = bias[col];
            const size_t mb = row0 + wr * 64 + mi * 16 + quad * 4;
            const int widx = (int)(mb >> 2);
            const int b = widx >> 10, rem = widx & 1023;
            const int h2 = rem >> 5, w2 = rem & 31;
            const size_t nb = ((size_t)b << 12) + (h2 << 7) + (w2 << 1);
            float* op = out + nb * 512 + coloff + col;
            op[0]            = acc[mi][ni][0] + bv;
            op[512]          = acc[mi][ni][1] + bv;
            op[64 * 512]     = acc[mi][ni][2] + bv;
            op[65 * 512]     = acc[mi][ni][3] + bv;
        }
}

// ---------------- fused lo-fi attention: kv-split, 8 waves x (64 q rows, half the kv) ----
// R0 structure per wave (proven 55us inner loop) but waves 0-3 process kv 0..511 and
// waves 4-7 process kv 512..1023 for the SAME q-rows. Doubles waves/SIMD (2->4) without
// duplicating per-iteration K-frag reads / exp2 / MFMA (R1's q-split mistake) -- only the
// one-time Q load and a final LDS merge of partial (O, l) are duplicated.
// S^T = K Q^T (16x16x32) leaves P[q=m16][kv=quad*4+r] in regs == A-frag of
// v_mfma_f32_16x16x16bf16_1k; PV consumes P directly. Q pre-scaled by 0.125*log2(e).
__global__ __launch_bounds__(512, 4) void k_attn(
        const unsigned short* __restrict__ qbuf,  // [32768,256] m'-order, pre-scaled
        const unsigned short* __restrict__ kbuf,  // [8192,256]
        const unsigned short* __restrict__ vT,    // [32][64][1024]
        unsigned short* __restrict__ aout) {      // [32768,256] m'-order
    // smem carving (shorts): K[half][buf] at (half*2+buf)*4608, V at 18432 + same.
    // 73728 B total -> 2 blocks/CU, 16 waves/CU. Reused as float scratch for the merge.
    __shared__ __align__(16) unsigned short smem[36864];
    const int tid = threadIdx.x;
    const int wave = tid >> 6, lane = tid & 63;
    const int half = wave >> 2, qw = wave & 3;
    const int m16 = lane & 15, quad = lane >> 4;
    const int qtile = blockIdx.x, bh = blockIdx.y;
    const int b = bh >> 2, h = bh & 3;

    // Q: 64 rows/wave (same rows in both halves)
    bf16x8 qf[4][2];
    const size_t qrow0 = (size_t)b * 4096 + qtile * 256 + qw * 64;
#pragma unroll
    for (int qh = 0; qh < 4; qh++) {
        const unsigned short* qp = qbuf + (qrow0 + qh * 16 + m16) * 256 + h * 64 + quad * 8;
        qf[qh][0] = as_bf16x8(*(const u32x4*)qp);
        qf[qh][1] = as_bf16x8(*(const u32x4*)(qp + 32));
    }

    f32x4 o[4][4] = {};
    float lp[4] = {0.f, 0.f, 0.f, 0.f};

    // staging: each half's 256 threads stage that half's K/V tiles
    const int sid = tid & 255;
    const int sr = sid >> 3;       // 0..31
    const int sc = sid & 7;        // 16B chunk
    const size_t kvoff = (size_t)half * 512;
    const unsigned short* kg = kbuf + ((size_t)b * 1024 + kvoff) * 256 + h * 64 + sc * 8;
    const unsigned short* vg = vT + ((size_t)bh * 64) * 1024 + kvoff + sc * 8;
    unsigned short* Kh = smem + half * 2 * 4608;           // [buf][64*72]
    unsigned short* Vh = smem + 18432 + half * 2 * 4608;

    u32x4 s0 = *(const u32x4*)(kg + (size_t)sr * 256);
    u32x4 s1 = *(const u32x4*)(kg + (size_t)(sr + 32) * 256);
    u32x4 s2 = *(const u32x4*)(vg + (size_t)sr * 1024);
    u32x4 s3 = *(const u32x4*)(vg + (size_t)(sr + 32) * 1024);
    *(u32x4*)&Kh[sr * 72 + sc * 8] = s0;
    *(u32x4*)&Kh[(sr + 32) * 72 + sc * 8] = s1;
    *(u32x4*)&Vh[sr * 72 + sc * 8] = s2;
    *(u32x4*)&Vh[(sr + 32) * 72 + sc * 8] = s3;

    for (int it = 0; it < 8; ++it) {
        const int cur = (it & 1) * 4608, nxt = cur ^ 4608;
        __syncthreads();
        if (it + 1 < 8) {
            const size_t kvb = (size_t)(it + 1) * 64;
            s0 = *(const u32x4*)(kg + (kvb + sr) * 256);
            s1 = *(const u32x4*)(kg + (kvb + sr + 32) * 256);
            s2 = *(const u32x4*)(vg + kvb + (size_t)sr * 1024);
            s3 = *(const u32x4*)(vg + kvb + (size_t)(sr + 32) * 1024);
        }

#pragma unroll
        for (int mt = 0; mt < 4; mt++) {
            // S^T = K Q^T : C col = q = m16, row = kv = mt*16 + quad*4 + r
            const unsigned short* kp = &Kh[cur + (mt * 16 + m16) * 72 + quad * 8];
            const bf16x8 kf0 = as_bf16x8(*(const u32x4*)kp);
            const bf16x8 kf1 = as_bf16x8(*(const u32x4*)(kp + 32));
            f32x4 st[4];
#pragma unroll
            for (int qh = 0; qh < 4; qh++) {
                f32x4 z = {};
                z = __builtin_amdgcn_mfma_f32_16x16x32_bf16(kf0, qf[qh][0], z, 0, 0, 0);
                st[qh] = __builtin_amdgcn_mfma_f32_16x16x32_bf16(kf1, qf[qh][1], z, 0, 0, 0);
            }
            // P = exp2(S') (scale pre-folded); packed P == K=16 MFMA A-frag
            i16x4 pa[4];
#pragma unroll
            for (int qh = 0; qh < 4; qh++) {
                float p0 = __builtin_exp2f(st[qh][0]);
                float p1 = __builtin_exp2f(st[qh][1]);
                float p2 = __builtin_exp2f(st[qh][2]);
                float p3 = __builtin_exp2f(st[qh][3]);
                lp[qh] += (p0 + p1) + (p2 + p3);
                u16x4 pk = { f2bf(p0), f2bf(p1), f2bf(p2), f2bf(p3) };
                pa[qh] = __builtin_bit_cast(i16x4, pk);
            }
            // O += P_chunk V_chunk  (K=16 MFMA, B-frag = V^T[d][mt*16 + quad*4 + j])
#pragma unroll
            for (int nt = 0; nt < 4; nt++) {
                const i16x4 vb = *(const i16x4*)&Vh[cur + (nt * 16 + m16) * 72 + mt * 16 + quad * 4];
#pragma unroll
                for (int qh = 0; qh < 4; qh++)
                    o[qh][nt] = __builtin_amdgcn_mfma_f32_16x16x16bf16_1k(pa[qh], vb, o[qh][nt], 0, 0, 0);
            }
        }

        if (it + 1 < 8) {
            *(u32x4*)&Kh[nxt + sr * 72 + sc * 8] = s0;
            *(u32x4*)&Kh[nxt + (sr + 32) * 72 + sc * 8] = s1;
            *(u32x4*)&Vh[nxt + sr * 72 + sc * 8] = s2;
            *(u32x4*)&Vh[nxt + (sr + 32) * 72 + sc * 8] = s3;
        }
    }

    // ---- merge the two kv-halves: half 1 dumps partials to LDS, half 0 combines ----
    __syncthreads();                            // everyone done reading K/V buffers
    float* scratch = (float*)smem;              // 18432 floats available; need 4*4352
    float* wbase = scratch + qw * 4352;
    if (half == 1) {
#pragma unroll
        for (int qh = 0; qh < 4; qh++)
#pragma unroll
            for (int nt = 0; nt < 4; nt++)
                *(f32x4*)&wbase[((qh * 4 + nt) * 64 + lane) * 4] = o[qh][nt];
#pragma unroll
        for (int qh = 0; qh < 4; qh++)
            wbase[4096 + qh * 64 + lane] = lp[qh];
    }
    __syncthreads();
    if (half == 0) {
#pragma unroll
        for (int qh = 0; qh < 4; qh++) {
#pragma unroll
            for (int nt = 0; nt < 4; nt++)
                o[qh][nt] += *(const f32x4*)&wbase[((qh * 4 + nt) * 64 + lane) * 4];
            lp[qh] += wbase[4096 + qh * 64 + lane];
        }
#pragma unroll
        for (int qh = 0; qh < 4; qh++) {
            float l = lp[qh];
            l += __shfl_xor(l, 16);
            l += __shfl_xor(l, 32);
            f32x4 linv;
#pragma unroll
            for (int r = 0; r < 4; r++)
                linv[r] = __builtin_amdgcn_rcpf(__shfl(l, quad * 4 + r));
#pragma unroll
            for (int nt = 0; nt < 4; nt++)
#pragma unroll
                for (int r = 0; r < 4; r++)
                    aout[(qrow0 + qh * 16 + quad * 4 + r) * 256 + h * 64 + nt * 16 + m16] =
                        f2bf(o[qh][nt][r] * linv[r]);
        }
    }
}

// ---------------- launcher ----------------

extern "C" void kernel_launch(void* const* d_in, const int* in_sizes, int n_in,
                              void* d_out, int out_size, void* d_ws, size_t ws_size,
                              hipStream_t stream) {
    (void)in_sizes; (void)n_in; (void)out_size; (void)ws_size;
    const float* x        = (const float*)d_in[0];
    const float* l_q_w    = (const float*)d_in[2];
    const float* l_kv_w   = (const float*)d_in[3];
    const float* l_proj_w = (const float*)d_in[4];
    const float* l_proj_b = (const float*)d_in[5];
    const float* h_qkv_w  = (const float*)d_in[6];
    const float* h_proj_w = (const float*)d_in[7];
    const float* h_proj_b = (const float*)d_in[8];
    float* out = (float*)d_out;

    char* ws = (char*)d_ws;
    unsigned short* xb     = (unsigned short*)(ws);             // 33.5MB, dead after mm512
    unsigned short* aout   = (unsigned short*)(ws);             // 16.8MB, overlays xb
    unsigned short* dbuf   = (unsigned short*)(ws + 33554432);  // 16.8MB
    unsigned short* qbuf   = (unsigned short*)(ws + 50331648);  // 16.8MB
    unsigned short* kbuf   = (unsigned short*)(ws + 67108864);  // 4.2MB
    unsigned short* vT     = (unsigned short*)(ws + 71303168);  // 4.2MB
    unsigned short* xpb    = (unsigned short*)(ws + 75497472);  // 8.4MB
    unsigned short* wcatT  = (unsigned short*)(ws + 83886080);
    unsigned short* lkvT   = (unsigned short*)(ws + 84410368);
    unsigned short* hprojT = (unsigned short*)(ws + 84934656);
    unsigned short* lprojT = (unsigned short*)(ws + 85065728);
    // total ws requirement: 85,196,800 B (same as prior rounds)

    // fused cast+pool (2048) + weight transpose (2560)
    k_prep<<<4608, 256, 0, stream>>>(x, h_qkv_w, l_q_w, l_kv_w, h_proj_w, l_proj_w,
                                     xb, xpb, wcatT, lkvT, hprojT, lprojT);
    // gemm1 (1024 blocks) + kv-gemm (256 blocks), fused hifi / V^T epilogues
    k_mm512<<<1280, 256, 0, stream>>>(xb, xpb, wcatT, lkvT, dbuf, qbuf, kbuf, vT);
    // attention, kv-split 8-wave blocks (aout overlays xb -- xb dead after mm512)
    k_attn<<<dim3(16, 32), 512, 0, stream>>>(qbuf, kbuf, vT, aout);
    // both projections + bias + un-permute into out
    k_mmproj<<<1024, 256, 0, stream>>>(dbuf, aout, hprojT, lprojT, h_proj_b, l_proj_b, out);
}

// Round 5
// 242.599 us; speedup vs baseline: 2.0622x; 2.0622x over previous
//
#include <hip/hip_runtime.h>

typedef __bf16 bf16x8 __attribute__((ext_vector_type(8)));
typedef float  f32x4  __attribute__((ext_vector_type(4)));
typedef unsigned int u32x4 __attribute__((ext_vector_type(4)));
typedef unsigned short u16x8 __attribute__((ext_vector_type(8)));
typedef unsigned short u16x4 __attribute__((ext_vector_type(4)));
typedef short i16x4 __attribute__((ext_vector_type(4)));

__device__ __forceinline__ unsigned short f2bf(float f) {
    return __builtin_bit_cast(unsigned short, (__bf16)f);
}
__device__ __forceinline__ bf16x8 as_bf16x8(u32x4 v) {
    return __builtin_bit_cast(bf16x8, v);
}

#define AS1 __attribute__((address_space(1)))
#define AS3 __attribute__((address_space(3)))
__device__ __forceinline__ void gload_lds16(const void* g, void* l) {
    __builtin_amdgcn_global_load_lds((const AS1 void*)g, (AS3 void*)l, 16, 0, 0);
}

// Window-major permutation: m' groups the 4 members of each 2x2 spatial
// window consecutively. n = b*4096 + hh*64 + ww  ->  m' = (b*1024 +
// (hh>>1)*32 + (ww>>1))*4 + (hh&1)*2 + (ww&1).

// ---------------- prep: fused cast+permute+pool (one x read), weight transpose ----------------
__global__ __launch_bounds__(256) void k_prep(
        const float* __restrict__ x,
        const float* __restrict__ h_qkv_w, const float* __restrict__ l_q_w,
        const float* __restrict__ l_kv_w, const float* __restrict__ h_proj_w,
        const float* __restrict__ l_proj_w,
        unsigned short* __restrict__ xb, unsigned short* __restrict__ xpb,
        unsigned short* __restrict__ wcatT, unsigned short* __restrict__ lkvT,
        unsigned short* __restrict__ hprojT, unsigned short* __restrict__ lprojT) {
    int blk = blockIdx.x;
    if (blk < 2048) {
        // thread -> (window widx, 8-channel chunk c8). Reads the 4 window rows once:
        // emits 4 xb rows (m'-order: consecutive!) + 1 pooled xpb row. x read once, not twice.
        int t = blk * 256 + threadIdx.x;
        int widx = t >> 6, c8 = (t & 63) << 3;
        int b = widx >> 10, rem = widx & 1023;
        int h2 = rem >> 5, w2 = rem & 31;
        const float* base = x + ((size_t)(b << 12) + (h2 << 7) + (w2 << 1)) * 512 + c8;
        f32x4 acc0 = {}, acc1 = {};
        const int roff[4] = {0, 1, 64, 65};   // (dh,dw) = (0,0),(0,1),(1,0),(1,1)
#pragma unroll
        for (int j = 0; j < 4; j++) {
            const float* src = base + (size_t)roff[j] * 512;
            f32x4 v0 = *(const f32x4*)src;
            f32x4 v1 = *(const f32x4*)(src + 4);
            acc0 += v0; acc1 += v1;
            u16x8 o = { f2bf(v0[0]), f2bf(v0[1]), f2bf(v0[2]), f2bf(v0[3]),
                        f2bf(v1[0]), f2bf(v1[1]), f2bf(v1[2]), f2bf(v1[3]) };
            *(u16x8*)(xb + ((size_t)widx * 4 + j) * 512 + c8) = o;
        }
        acc0 *= 0.25f; acc1 *= 0.25f;
        u16x8 p = { f2bf(acc0[0]), f2bf(acc0[1]), f2bf(acc0[2]), f2bf(acc0[3]),
                    f2bf(acc1[0]), f2bf(acc1[1]), f2bf(acc1[2]), f2bf(acc1[3]) };
        *(u16x8*)(xpb + (size_t)widx * 512 + c8) = p;
    } else {
        // weights -> B^T bf16
        int i = (blk - 2048) * 256 + threadIdx.x;
        if (i < 262144) {
            int n = i >> 9, k = i & 511;
            float v = (n < 256) ? h_qkv_w[k * 256 + n] : l_q_w[k * 256 + (n - 256)];
            wcatT[i] = f2bf(v);
        } else if (i < 524288) {
            int j = i - 262144; int n = j >> 9, k = j & 511;
            lkvT[j] = f2bf(l_kv_w[k * 512 + n]);
        } else if (i < 589824) {
            int j = i - 524288; int n = j >> 8, k = j & 255;
            hprojT[j] = f2bf(h_proj_w[k * 256 + n]);
        } else {
            int j = i - 589824; int n = j >> 8, k = j & 255;
            lprojT[j] = f2bf(l_proj_w[k * 256 + n]);
        }
    }
}

// ---------------- shared GEMM core: 128x128 tile, BK=32 (m97 structure) ----------------
__device__ __forceinline__ void mm_core(
        const unsigned short* __restrict__ A, const unsigned short* __restrict__ Bt,
        size_t row0, int col0, int K,
        unsigned short* As, unsigned short* Bs, f32x4 (&acc)[4][4]) {
    const int tid = threadIdx.x;
    const int wave = tid >> 6, lane = tid & 63;
    const int m16 = lane & 15, quad = lane >> 4;
    const int wr = wave >> 1, wc = wave & 1;
    const int srow = lane >> 2;
    const int scol = (lane & 3) * 8;
    const unsigned short* Ap0 = A + (row0 + wave * 32 + srow) * (size_t)K + scol;
    const unsigned short* Ap1 = Ap0 + (size_t)16 * K;
    const unsigned short* Bp0 = Bt + (size_t)(col0 + wave * 32 + srow) * K + scol;
    const unsigned short* Bp1 = Bp0 + (size_t)16 * K;
    unsigned short* Al0 = As + wave * 1024;
    unsigned short* Al1 = As + wave * 1024 + 512;
    unsigned short* Bl0 = Bs + wave * 1024;
    unsigned short* Bl1 = Bs + wave * 1024 + 512;

    for (int k0 = 0; k0 < K; k0 += 32) {
        __syncthreads();
        gload_lds16(Ap0 + k0, Al0);
        gload_lds16(Ap1 + k0, Al1);
        gload_lds16(Bp0 + k0, Bl0);
        gload_lds16(Bp1 + k0, Bl1);
        __syncthreads();
        bf16x8 af[4], bfr[4];
#pragma unroll
        for (int mi = 0; mi < 4; mi++)
            af[mi] = as_bf16x8(*(const u32x4*)(As + (wr * 64 + mi * 16 + m16) * 32 + quad * 8));
#pragma unroll
        for (int ni = 0; ni < 4; ni++)
            bfr[ni] = as_bf16x8(*(const u32x4*)(Bs + (wc * 64 + ni * 16 + m16) * 32 + quad * 8));
#pragma unroll
        for (int mi = 0; mi < 4; mi++)
#pragma unroll
            for (int ni = 0; ni < 4; ni++)
                acc[mi][ni] = __builtin_amdgcn_mfma_f32_16x16x32_bf16(af[mi], bfr[ni], acc[mi][ni], 0, 0, 0);
    }
}

// ---------------- launch 2: gemm1 (x@[hqkv|lq] + fused hifi) and kv-gemm (+fused V^T) ----------------
// XCD-chunked swizzle: consecutive original flat ids (= same A row-stripe, different
// col tile) are placed on the SAME XCD so the stripe is fetched into one L2 once.
__global__ __launch_bounds__(256, 2) void k_mm512(
        const unsigned short* __restrict__ xb, const unsigned short* __restrict__ xpb,
        const unsigned short* __restrict__ wcatT, const unsigned short* __restrict__ lkvT,
        unsigned short* __restrict__ dbuf, unsigned short* __restrict__ qbuf,
        unsigned short* __restrict__ kbuf, unsigned short* __restrict__ vT) {
    __shared__ __align__(16) unsigned short As[128 * 32];
    __shared__ __align__(16) unsigned short Bs[128 * 32];
    const int bid = blockIdx.x;                       // 0..1279, 1280%8==0 -> bijective
    const int flat = (bid & 7) * 160 + (bid >> 3);
    const bool isg1 = flat < 1024;
    const unsigned short* A;
    const unsigned short* Bt;
    size_t row0; int col0;
    if (isg1) { A = xb;  Bt = wcatT; row0 = (size_t)(flat >> 2) * 128; col0 = (flat & 3) * 128; }
    else { int f = flat - 1024; A = xpb; Bt = lkvT; row0 = (size_t)(f >> 2) * 128; col0 = (f & 3) * 128; }

    f32x4 acc[4][4] = {};
    mm_core(A, Bt, row0, col0, 512, As, Bs, acc);

    const int tid = threadIdx.x;
    const int wave = tid >> 6, lane = tid & 63;
    const int m16 = lane & 15, quad = lane >> 4;
    const int wr = wave >> 1, wc = wave & 1;

    if (isg1) {
        if (col0 < 256) {
            // hifi: lane's 4 rows are one 2x2 window (m'-order) -> dbuf = mean - val
#pragma unroll
            for (int mi = 0; mi < 4; mi++)
#pragma unroll
                for (int ni = 0; ni < 4; ni++) {
                    const int col = col0 + wc * 64 + ni * 16 + m16;
                    const size_t mb = row0 + wr * 64 + mi * 16 + quad * 4;
                    float v0 = acc[mi][ni][0], v1 = acc[mi][ni][1];
                    float v2 = acc[mi][ni][2], v3 = acc[mi][ni][3];
                    float m = 0.25f * ((v0 + v1) + (v2 + v3));
                    dbuf[(mb + 0) * 256 + col] = f2bf(m - v0);
                    dbuf[(mb + 1) * 256 + col] = f2bf(m - v1);
                    dbuf[(mb + 2) * 256 + col] = f2bf(m - v2);
                    dbuf[(mb + 3) * 256 + col] = f2bf(m - v3);
                }
        } else {
            // Q: fold softmax scale (0.125) and log2(e) into Q so attn uses exp2 directly
#pragma unroll
            for (int mi = 0; mi < 4; mi++)
#pragma unroll
                for (int ni = 0; ni < 4; ni++) {
                    const int col = col0 - 256 + wc * 64 + ni * 16 + m16;
                    const size_t mb = row0 + wr * 64 + mi * 16 + quad * 4;
#pragma unroll
                    for (int r = 0; r < 4; r++)
                        qbuf[(mb + r) * 256 + col] = f2bf(acc[mi][ni][r] * 0.18033688f);
                }
        }
    } else {
        if (col0 < 256) {
#pragma unroll
            for (int mi = 0; mi < 4; mi++)
#pragma unroll
                for (int ni = 0; ni < 4; ni++) {
                    const int col = col0 + wc * 64 + ni * 16 + m16;
                    const size_t row = row0 + wr * 64 + mi * 16 + quad * 4;
#pragma unroll
                    for (int r = 0; r < 4; r++)
                        kbuf[(row + r) * 256 + col] = f2bf(acc[mi][ni][r]);
                }
        } else {
            // V stored transposed: vT[(b*4+h)*64 + d][kv], lane's 4 rows = 4 consecutive kv
#pragma unroll
            for (int mi = 0; mi < 4; mi++)
#pragma unroll
                for (int ni = 0; ni < 4; ni++) {
                    const int d = col0 - 256 + wc * 64 + ni * 16 + m16;
                    const int hh = d >> 6, dd = d & 63;
                    const size_t kvg = row0 + wr * 64 + mi * 16 + quad * 4;
                    const int b = (int)(kvg >> 10), kv = (int)(kvg & 1023);
                    u16x4 pk = { f2bf(acc[mi][ni][0]), f2bf(acc[mi][ni][1]),
                                 f2bf(acc[mi][ni][2]), f2bf(acc[mi][ni][3]) };
                    *(u16x4*)(vT + (((size_t)(b * 4 + hh) * 64 + dd) << 10) + kv) = pk;
                }
        }
    }
}

// ---------------- launch 4: both projection GEMMs, un-permuting epilogue ----------------
__global__ __launch_bounds__(256, 2) void k_mmproj(
        const unsigned short* __restrict__ dbuf, const unsigned short* __restrict__ aout,
        const unsigned short* __restrict__ hprojT, const unsigned short* __restrict__ lprojT,
        const float* __restrict__ h_proj_b, const float* __restrict__ l_proj_b,
        float* __restrict__ out) {
    __shared__ __align__(16) unsigned short As[128 * 32];
    __shared__ __align__(16) unsigned short Bs[128 * 32];
    const int bid = blockIdx.x;                       // 0..1023, 1024%8==0 -> bijective
    const int flat = (bid & 7) * 128 + (bid >> 3);
    const bool hi = flat < 512;
    const int f = flat & 511;
    const unsigned short* A  = hi ? dbuf : aout;
    const unsigned short* Bt = hi ? hprojT : lprojT;
    const float* bias = hi ? h_proj_b : l_proj_b;
    const int coloff = hi ? 0 : 256;
    const size_t row0 = (size_t)(f >> 1) * 128;
    const int col0 = (f & 1) * 128;

    f32x4 acc[4][4] = {};
    mm_core(A, Bt, row0, col0, 256, As, Bs, acc);

    const int tid = threadIdx.x;
    const int wave = tid >> 6, lane = tid & 63;
    const int m16 = lane & 15, quad = lane >> 4;
    const int wr = wave >> 1, wc = wave & 1;

#pragma unroll
    for (int mi = 0; mi < 4; mi++)
#pragma unroll
        for (int ni = 0; ni < 4; ni++) {
            const int col = col0 + wc * 64 + ni * 16 + m16;
            const float bv = bias[col];
            const size_t mb = row0 + wr * 64 + mi * 16 + quad * 4;
            const int widx = (int)(mb >> 2);
            const int b = widx >> 10, rem = widx & 1023;
            const int h2 = rem >> 5, w2 = rem & 31;
            const size_t nb = ((size_t)b << 12) + (h2 << 7) + (w2 << 1);
            float* op = out + nb * 512 + coloff + col;
            op[0]            = acc[mi][ni][0] + bv;
            op[512]          = acc[mi][ni][1] + bv;
            op[64 * 512]     = acc[mi][ni][2] + bv;
            op[65 * 512]     = acc[mi][ni][3] + bv;
        }
}

// ---------------- fused lo-fi attention: 4 waves x 64 q rows, no P round-trip ----------------
// Round-0 proven structure (55.2us): 256 thr, (256,2), 124 VGPR, lp on VALU, no setprio.
// S^T = K Q^T (16x16x32) leaves P[q=m16][kv=quad*4+r] in registers -- exactly the
// A-fragment layout of v_mfma_f32_16x16x16bf16_1k. PV consumes P directly from regs.
// Only delta vs round 0: Q arrives pre-scaled by 0.125*log2(e) -> raw v_exp_f32.
// NOTE (R2/R4 lesson): __launch_bounds__ second arg >= 4 clamps VGPR to 64 and spills
// this kernel catastrophically. Do not touch the (256,2).
__global__ __launch_bounds__(256, 2) void k_attn(
        const unsigned short* __restrict__ qbuf,  // [32768,256] m'-order, pre-scaled
        const unsigned short* __restrict__ kbuf,  // [8192,256]
        const unsigned short* __restrict__ vT,    // [32][64][1024]
        unsigned short* __restrict__ aout) {      // [32768,256] m'-order
    __shared__ __align__(16) unsigned short Kb[2][64 * 72];   // [kv][d], pad 72
    __shared__ __align__(16) unsigned short Vb[2][64 * 72];   // [d][kv], pad 72
    const int tid = threadIdx.x;
    const int wave = tid >> 6, lane = tid & 63;
    const int m16 = lane & 15, quad = lane >> 4;
    const int qtile = blockIdx.x, bh = blockIdx.y;
    const int b = bh >> 2, h = bh & 3;

    // Q: 64 rows/wave
    bf16x8 qf[4][2];
    const size_t qrow0 = (size_t)b * 4096 + qtile * 256 + wave * 64;
#pragma unroll
    for (int qh = 0; qh < 4; qh++) {
        const unsigned short* qp = qbuf + (qrow0 + qh * 16 + m16) * 256 + h * 64 + quad * 8;
        qf[qh][0] = as_bf16x8(*(const u32x4*)qp);
        qf[qh][1] = as_bf16x8(*(const u32x4*)(qp + 32));
    }

    f32x4 o[4][4] = {};
    float lp[4] = {0.f, 0.f, 0.f, 0.f};

    // staging: 256 threads x (2 K rows + 2 V rows) x 16B
    const int sr = tid >> 3;       // 0..31
    const int sc = tid & 7;        // 16B chunk
    const unsigned short* kg = kbuf + ((size_t)b * 1024) * 256 + h * 64 + sc * 8;
    const unsigned short* vg = vT + ((size_t)bh * 64) * 1024 + sc * 8;

    u32x4 s0 = *(const u32x4*)(kg + (size_t)sr * 256);
    u32x4 s1 = *(const u32x4*)(kg + (size_t)(sr + 32) * 256);
    u32x4 s2 = *(const u32x4*)(vg + (size_t)sr * 1024);
    u32x4 s3 = *(const u32x4*)(vg + (size_t)(sr + 32) * 1024);
    *(u32x4*)&Kb[0][sr * 72 + sc * 8] = s0;
    *(u32x4*)&Kb[0][(sr + 32) * 72 + sc * 8] = s1;
    *(u32x4*)&Vb[0][sr * 72 + sc * 8] = s2;
    *(u32x4*)&Vb[0][(sr + 32) * 72 + sc * 8] = s3;

    for (int it = 0; it < 16; ++it) {
        const int cur = it & 1, nxt = cur ^ 1;
        __syncthreads();
        if (it + 1 < 16) {
            const size_t kvb = (size_t)(it + 1) * 64;
            s0 = *(const u32x4*)(kg + (kvb + sr) * 256);
            s1 = *(const u32x4*)(kg + (kvb + sr + 32) * 256);
            s2 = *(const u32x4*)(vg + kvb + (size_t)sr * 1024);
            s3 = *(const u32x4*)(vg + kvb + (size_t)(sr + 32) * 1024);
        }

#pragma unroll
        for (int mt = 0; mt < 4; mt++) {
            // S^T = K Q^T : C col = q = m16, row = kv = mt*16 + quad*4 + r
            const unsigned short* kp = &Kb[cur][(mt * 16 + m16) * 72 + quad * 8];
            const bf16x8 kf0 = as_bf16x8(*(const u32x4*)kp);
            const bf16x8 kf1 = as_bf16x8(*(const u32x4*)(kp + 32));
            f32x4 st[4];
#pragma unroll
            for (int qh = 0; qh < 4; qh++) {
                f32x4 z = {};
                z = __builtin_amdgcn_mfma_f32_16x16x32_bf16(kf0, qf[qh][0], z, 0, 0, 0);
                st[qh] = __builtin_amdgcn_mfma_f32_16x16x32_bf16(kf1, qf[qh][1], z, 0, 0, 0);
            }
            // P = exp2(S') (scale pre-folded into Q); packed P == K=16 MFMA A-frag
            i16x4 pa[4];
#pragma unroll
            for (int qh = 0; qh < 4; qh++) {
                float p0 = __builtin_exp2f(st[qh][0]);
                float p1 = __builtin_exp2f(st[qh][1]);
                float p2 = __builtin_exp2f(st[qh][2]);
                float p3 = __builtin_exp2f(st[qh][3]);
                lp[qh] += (p0 + p1) + (p2 + p3);
                u16x4 pk = { f2bf(p0), f2bf(p1), f2bf(p2), f2bf(p3) };
                pa[qh] = __builtin_bit_cast(i16x4, pk);
            }
            // O += P_chunk V_chunk  (K=16 MFMA, B-frag = V^T[d][mt*16 + quad*4 + j])
#pragma unroll
            for (int nt = 0; nt < 4; nt++) {
                const i16x4 vb = *(const i16x4*)&Vb[cur][(nt * 16 + m16) * 72 + mt * 16 + quad * 4];
#pragma unroll
                for (int qh = 0; qh < 4; qh++)
                    o[qh][nt] = __builtin_amdgcn_mfma_f32_16x16x16bf16_1k(pa[qh], vb, o[qh][nt], 0, 0, 0);
            }
        }

        if (it + 1 < 16) {
            *(u32x4*)&Kb[nxt][sr * 72 + sc * 8] = s0;
            *(u32x4*)&Kb[nxt][(sr + 32) * 72 + sc * 8] = s1;
            *(u32x4*)&Vb[nxt][sr * 72 + sc * 8] = s2;
            *(u32x4*)&Vb[nxt][(sr + 32) * 72 + sc * 8] = s3;
        }
    }

#pragma unroll
    for (int qh = 0; qh < 4; qh++) {
        float l = lp[qh];
        l += __shfl_xor(l, 16);
        l += __shfl_xor(l, 32);
        f32x4 linv;
#pragma unroll
        for (int r = 0; r < 4; r++)
            linv[r] = __builtin_amdgcn_rcpf(__shfl(l, quad * 4 + r));
#pragma unroll
        for (int nt = 0; nt < 4; nt++)
#pragma unroll
            for (int r = 0; r < 4; r++)
                aout[(qrow0 + qh * 16 + quad * 4 + r) * 256 + h * 64 + nt * 16 + m16] =
                    f2bf(o[qh][nt][r] * linv[r]);
    }
}

// ---------------- launcher ----------------

extern "C" void kernel_launch(void* const* d_in, const int* in_sizes, int n_in,
                              void* d_out, int out_size, void* d_ws, size_t ws_size,
                              hipStream_t stream) {
    (void)in_sizes; (void)n_in; (void)out_size; (void)ws_size;
    const float* x        = (const float*)d_in[0];
    const float* l_q_w    = (const float*)d_in[2];
    const float* l_kv_w   = (const float*)d_in[3];
    const float* l_proj_w = (const float*)d_in[4];
    const float* l_proj_b = (const float*)d_in[5];
    const float* h_qkv_w  = (const float*)d_in[6];
    const float* h_proj_w = (const float*)d_in[7];
    const float* h_proj_b = (const float*)d_in[8];
    float* out = (float*)d_out;

    char* ws = (char*)d_ws;
    unsigned short* xb     = (unsigned short*)(ws);             // 33.5MB, dead after mm512
    unsigned short* aout   = (unsigned short*)(ws);             // 16.8MB, overlays xb
    unsigned short* dbuf   = (unsigned short*)(ws + 33554432);  // 16.8MB
    unsigned short* qbuf   = (unsigned short*)(ws + 50331648);  // 16.8MB
    unsigned short* kbuf   = (unsigned short*)(ws + 67108864);  // 4.2MB
    unsigned short* vT     = (unsigned short*)(ws + 71303168);  // 4.2MB
    unsigned short* xpb    = (unsigned short*)(ws + 75497472);  // 8.4MB
    unsigned short* wcatT  = (unsigned short*)(ws + 83886080);
    unsigned short* lkvT   = (unsigned short*)(ws + 84410368);
    unsigned short* hprojT = (unsigned short*)(ws + 84934656);
    unsigned short* lprojT = (unsigned short*)(ws + 85065728);
    // total ws requirement: 85,196,800 B (same as prior rounds)

    // fused cast+pool (2048) + weight transpose (2560)
    k_prep<<<4608, 256, 0, stream>>>(x, h_qkv_w, l_q_w, l_kv_w, h_proj_w, l_proj_w,
                                     xb, xpb, wcatT, lkvT, hprojT, lprojT);
    // gemm1 (1024 blocks) + kv-gemm (256 blocks), fused hifi / V^T epilogues, XCD swizzle
    k_mm512<<<1280, 256, 0, stream>>>(xb, xpb, wcatT, lkvT, dbuf, qbuf, kbuf, vT);
    // attention (aout overlays xb -- xb dead after mm512)
    k_attn<<<dim3(16, 32), 256, 0, stream>>>(qbuf, kbuf, vT, aout);
    // both projections + bias + un-permute into out, XCD swizzle
    k_mmproj<<<1024, 256, 0, stream>>>(dbuf, aout, hprojT, lprojT, h_proj_b, l_proj_b, out);
}

// Round 6
// 233.041 us; speedup vs baseline: 2.1468x; 1.0410x over previous
//
#include <hip/hip_runtime.h>

typedef __bf16 bf16x8 __attribute__((ext_vector_type(8)));
typedef float  f32x4  __attribute__((ext_vector_type(4)));
typedef unsigned int u32x4 __attribute__((ext_vector_type(4)));
typedef unsigned short u16x8 __attribute__((ext_vector_type(8)));
typedef unsigned short u16x4 __attribute__((ext_vector_type(4)));
typedef short i16x4 __attribute__((ext_vector_type(4)));

__device__ __forceinline__ unsigned short f2bf(float f) {
    return __builtin_bit_cast(unsigned short, (__bf16)f);
}
__device__ __forceinline__ bf16x8 as_bf16x8(u32x4 v) {
    return __builtin_bit_cast(bf16x8, v);
}

#define AS1 __attribute__((address_space(1)))
#define AS3 __attribute__((address_space(3)))
__device__ __forceinline__ void gload_lds16(const void* g, void* l) {
    __builtin_amdgcn_global_load_lds((const AS1 void*)g, (AS3 void*)l, 16, 0, 0);
}

// Window-major permutation: m' groups the 4 members of each 2x2 spatial
// window consecutively. n = b*4096 + hh*64 + ww  ->  m' = (b*1024 +
// (hh>>1)*32 + (ww>>1))*4 + (hh&1)*2 + (ww&1).

// ---------------- prep: fused cast+permute+pool (one x read), weight transpose ----------------
__global__ __launch_bounds__(256) void k_prep(
        const float* __restrict__ x,
        const float* __restrict__ h_qkv_w, const float* __restrict__ l_q_w,
        const float* __restrict__ l_kv_w, const float* __restrict__ h_proj_w,
        const float* __restrict__ l_proj_w,
        unsigned short* __restrict__ xb, unsigned short* __restrict__ xpb,
        unsigned short* __restrict__ wcatT, unsigned short* __restrict__ lkvT,
        unsigned short* __restrict__ hprojT, unsigned short* __restrict__ lprojT) {
    int blk = blockIdx.x;
    if (blk < 2048) {
        // thread -> (window widx, 8-channel chunk c8). Reads the 4 window rows once:
        // emits 4 xb rows (m'-order: consecutive!) + 1 pooled xpb row. x read once, not twice.
        int t = blk * 256 + threadIdx.x;
        int widx = t >> 6, c8 = (t & 63) << 3;
        int b = widx >> 10, rem = widx & 1023;
        int h2 = rem >> 5, w2 = rem & 31;
        const float* base = x + ((size_t)(b << 12) + (h2 << 7) + (w2 << 1)) * 512 + c8;
        f32x4 acc0 = {}, acc1 = {};
        const int roff[4] = {0, 1, 64, 65};   // (dh,dw) = (0,0),(0,1),(1,0),(1,1)
#pragma unroll
        for (int j = 0; j < 4; j++) {
            const float* src = base + (size_t)roff[j] * 512;
            f32x4 v0 = *(const f32x4*)src;
            f32x4 v1 = *(const f32x4*)(src + 4);
            acc0 += v0; acc1 += v1;
            u16x8 o = { f2bf(v0[0]), f2bf(v0[1]), f2bf(v0[2]), f2bf(v0[3]),
                        f2bf(v1[0]), f2bf(v1[1]), f2bf(v1[2]), f2bf(v1[3]) };
            *(u16x8*)(xb + ((size_t)widx * 4 + j) * 512 + c8) = o;
        }
        acc0 *= 0.25f; acc1 *= 0.25f;
        u16x8 p = { f2bf(acc0[0]), f2bf(acc0[1]), f2bf(acc0[2]), f2bf(acc0[3]),
                    f2bf(acc1[0]), f2bf(acc1[1]), f2bf(acc1[2]), f2bf(acc1[3]) };
        *(u16x8*)(xpb + (size_t)widx * 512 + c8) = p;
    } else {
        // weights -> B^T bf16
        int i = (blk - 2048) * 256 + threadIdx.x;
        if (i < 262144) {
            int n = i >> 9, k = i & 511;
            float v = (n < 256) ? h_qkv_w[k * 256 + n] : l_q_w[k * 256 + (n - 256)];
            wcatT[i] = f2bf(v);
        } else if (i < 524288) {
            int j = i - 262144; int n = j >> 9, k = j & 511;
            lkvT[j] = f2bf(l_kv_w[k * 512 + n]);
        } else if (i < 589824) {
            int j = i - 524288; int n = j >> 8, k = j & 255;
            hprojT[j] = f2bf(h_proj_w[k * 256 + n]);
        } else {
            int j = i - 589824; int n = j >> 8, k = j & 255;
            lprojT[j] = f2bf(l_proj_w[k * 256 + n]);
        }
    }
}

// ---------------- shared GEMM core: 128x128 tile, BK=32 (m97 structure) ----------------
__device__ __forceinline__ void mm_core(
        const unsigned short* __restrict__ A, const unsigned short* __restrict__ Bt,
        size_t row0, int col0, int K,
        unsigned short* As, unsigned short* Bs, f32x4 (&acc)[4][4]) {
    const int tid = threadIdx.x;
    const int wave = tid >> 6, lane = tid & 63;
    const int m16 = lane & 15, quad = lane >> 4;
    const int wr = wave >> 1, wc = wave & 1;
    const int srow = lane >> 2;
    const int scol = (lane & 3) * 8;
    const unsigned short* Ap0 = A + (row0 + wave * 32 + srow) * (size_t)K + scol;
    const unsigned short* Ap1 = Ap0 + (size_t)16 * K;
    const unsigned short* Bp0 = Bt + (size_t)(col0 + wave * 32 + srow) * K + scol;
    const unsigned short* Bp1 = Bp0 + (size_t)16 * K;
    unsigned short* Al0 = As + wave * 1024;
    unsigned short* Al1 = As + wave * 1024 + 512;
    unsigned short* Bl0 = Bs + wave * 1024;
    unsigned short* Bl1 = Bs + wave * 1024 + 512;

    for (int k0 = 0; k0 < K; k0 += 32) {
        __syncthreads();
        gload_lds16(Ap0 + k0, Al0);
        gload_lds16(Ap1 + k0, Al1);
        gload_lds16(Bp0 + k0, Bl0);
        gload_lds16(Bp1 + k0, Bl1);
        __syncthreads();
        bf16x8 af[4], bfr[4];
#pragma unroll
        for (int mi = 0; mi < 4; mi++)
            af[mi] = as_bf16x8(*(const u32x4*)(As + (wr * 64 + mi * 16 + m16) * 32 + quad * 8));
#pragma unroll
        for (int ni = 0; ni < 4; ni++)
            bfr[ni] = as_bf16x8(*(const u32x4*)(Bs + (wc * 64 + ni * 16 + m16) * 32 + quad * 8));
#pragma unroll
        for (int mi = 0; mi < 4; mi++)
#pragma unroll
            for (int ni = 0; ni < 4; ni++)
                acc[mi][ni] = __builtin_amdgcn_mfma_f32_16x16x32_bf16(af[mi], bfr[ni], acc[mi][ni], 0, 0, 0);
    }
}

// ---------------- launch 2: gemm1 (x@[hqkv|lq] + fused hifi) and kv-gemm (+fused V^T) ----------------
// XCD-chunked swizzle: consecutive original flat ids (= same A row-stripe, different
// col tile) are placed on the SAME XCD so the stripe is fetched into one L2 once.
__global__ __launch_bounds__(256, 2) void k_mm512(
        const unsigned short* __restrict__ xb, const unsigned short* __restrict__ xpb,
        const unsigned short* __restrict__ wcatT, const unsigned short* __restrict__ lkvT,
        unsigned short* __restrict__ dbuf, unsigned short* __restrict__ qbuf,
        unsigned short* __restrict__ kbuf, unsigned short* __restrict__ vT) {
    __shared__ __align__(16) unsigned short As[128 * 32];
    __shared__ __align__(16) unsigned short Bs[128 * 32];
    const int bid = blockIdx.x;                       // 0..1279, 1280%8==0 -> bijective
    const int flat = (bid & 7) * 160 + (bid >> 3);
    const bool isg1 = flat < 1024;
    const unsigned short* A;
    const unsigned short* Bt;
    size_t row0; int col0;
    if (isg1) { A = xb;  Bt = wcatT; row0 = (size_t)(flat >> 2) * 128; col0 = (flat & 3) * 128; }
    else { int f = flat - 1024; A = xpb; Bt = lkvT; row0 = (size_t)(f >> 2) * 128; col0 = (f & 3) * 128; }

    f32x4 acc[4][4] = {};
    mm_core(A, Bt, row0, col0, 512, As, Bs, acc);

    const int tid = threadIdx.x;
    const int wave = tid >> 6, lane = tid & 63;
    const int m16 = lane & 15, quad = lane >> 4;
    const int wr = wave >> 1, wc = wave & 1;

    if (isg1) {
        if (col0 < 256) {
            // hifi: lane's 4 rows are one 2x2 window (m'-order) -> dbuf = mean - val
#pragma unroll
            for (int mi = 0; mi < 4; mi++)
#pragma unroll
                for (int ni = 0; ni < 4; ni++) {
                    const int col = col0 + wc * 64 + ni * 16 + m16;
                    const size_t mb = row0 + wr * 64 + mi * 16 + quad * 4;
                    float v0 = acc[mi][ni][0], v1 = acc[mi][ni][1];
                    float v2 = acc[mi][ni][2], v3 = acc[mi][ni][3];
                    float m = 0.25f * ((v0 + v1) + (v2 + v3));
                    dbuf[(mb + 0) * 256 + col] = f2bf(m - v0);
                    dbuf[(mb + 1) * 256 + col] = f2bf(m - v1);
                    dbuf[(mb + 2) * 256 + col] = f2bf(m - v2);
                    dbuf[(mb + 3) * 256 + col] = f2bf(m - v3);
                }
        } else {
            // Q (unscaled -- R5 lesson: softmax scale stays in k_attn's __expf, whose
            // v_mul co-issues for free; __builtin_exp2f's denormal-guard lowering cost
            // ~14us of serial VALU)
#pragma unroll
            for (int mi = 0; mi < 4; mi++)
#pragma unroll
                for (int ni = 0; ni < 4; ni++) {
                    const int col = col0 - 256 + wc * 64 + ni * 16 + m16;
                    const size_t mb = row0 + wr * 64 + mi * 16 + quad * 4;
#pragma unroll
                    for (int r = 0; r < 4; r++)
                        qbuf[(mb + r) * 256 + col] = f2bf(acc[mi][ni][r]);
                }
        }
    } else {
        if (col0 < 256) {
#pragma unroll
            for (int mi = 0; mi < 4; mi++)
#pragma unroll
                for (int ni = 0; ni < 4; ni++) {
                    const int col = col0 + wc * 64 + ni * 16 + m16;
                    const size_t row = row0 + wr * 64 + mi * 16 + quad * 4;
#pragma unroll
                    for (int r = 0; r < 4; r++)
                        kbuf[(row + r) * 256 + col] = f2bf(acc[mi][ni][r]);
                }
        } else {
            // V stored transposed: vT[(b*4+h)*64 + d][kv], lane's 4 rows = 4 consecutive kv
#pragma unroll
            for (int mi = 0; mi < 4; mi++)
#pragma unroll
                for (int ni = 0; ni < 4; ni++) {
                    const int d = col0 - 256 + wc * 64 + ni * 16 + m16;
                    const int hh = d >> 6, dd = d & 63;
                    const size_t kvg = row0 + wr * 64 + mi * 16 + quad * 4;
                    const int b = (int)(kvg >> 10), kv = (int)(kvg & 1023);
                    u16x4 pk = { f2bf(acc[mi][ni][0]), f2bf(acc[mi][ni][1]),
                                 f2bf(acc[mi][ni][2]), f2bf(acc[mi][ni][3]) };
                    *(u16x4*)(vT + (((size_t)(b * 4 + hh) * 64 + dd) << 10) + kv) = pk;
                }
        }
    }
}

// ---------------- launch 4: both projection GEMMs, un-permuting epilogue ----------------
__global__ __launch_bounds__(256, 2) void k_mmproj(
        const unsigned short* __restrict__ dbuf, const unsigned short* __restrict__ aout,
        const unsigned short* __restrict__ hprojT, const unsigned short* __restrict__ lprojT,
        const float* __restrict__ h_proj_b, const float* __restrict__ l_proj_b,
        float* __restrict__ out) {
    __shared__ __align__(16) unsigned short As[128 * 32];
    __shared__ __align__(16) unsigned short Bs[128 * 32];
    const int bid = blockIdx.x;                       // 0..1023, 1024%8==0 -> bijective
    const int flat = (bid & 7) * 128 + (bid >> 3);
    const bool hi = flat < 512;
    const int f = flat & 511;
    const unsigned short* A  = hi ? dbuf : aout;
    const unsigned short* Bt = hi ? hprojT : lprojT;
    const float* bias = hi ? h_proj_b : l_proj_b;
    const int coloff = hi ? 0 : 256;
    const size_t row0 = (size_t)(f >> 1) * 128;
    const int col0 = (f & 1) * 128;

    f32x4 acc[4][4] = {};
    mm_core(A, Bt, row0, col0, 256, As, Bs, acc);

    const int tid = threadIdx.x;
    const int wave = tid >> 6, lane = tid & 63;
    const int m16 = lane & 15, quad = lane >> 4;
    const int wr = wave >> 1, wc = wave & 1;

#pragma unroll
    for (int mi = 0; mi < 4; mi++)
#pragma unroll
        for (int ni = 0; ni < 4; ni++) {
            const int col = col0 + wc * 64 + ni * 16 + m16;
            const float bv = bias[col];
            const size_t mb = row0 + wr * 64 + mi * 16 + quad * 4;
            const int widx = (int)(mb >> 2);
            const int b = widx >> 10, rem = widx & 1023;
            const int h2 = rem >> 5, w2 = rem & 31;
            const size_t nb = ((size_t)b << 12) + (h2 << 7) + (w2 << 1);
            float* op = out + nb * 512 + coloff + col;
            op[0]            = acc[mi][ni][0] + bv;
            op[512]          = acc[mi][ni][1] + bv;
            op[64 * 512]     = acc[mi][ni][2] + bv;
            op[65 * 512]     = acc[mi][ni][3] + bv;
        }
}

// ---------------- fused lo-fi attention: 4 waves x 64 q rows, no P round-trip ----------------
// EXACT round-0 proven kernel (55.2us): 256 thr, (256,2), __expf(st*0.125f) -- the
// v_mul co-issues; do NOT replace with __builtin_exp2f (denormal-guard lowering, R5).
// Do NOT touch __launch_bounds__ (R2/R4: min-waves>=4 clamps VGPR to 64 -> spill).
// S^T = K Q^T (16x16x32) leaves P[q=m16][kv=quad*4+r] in registers -- exactly the
// A-fragment layout of v_mfma_f32_16x16x16bf16_1k. PV consumes P directly from regs.
__global__ __launch_bounds__(256, 2) void k_attn(
        const unsigned short* __restrict__ qbuf,  // [32768,256] m'-order
        const unsigned short* __restrict__ kbuf,  // [8192,256]
        const unsigned short* __restrict__ vT,    // [32][64][1024]
        unsigned short* __restrict__ aout) {      // [32768,256] m'-order
    __shared__ __align__(16) unsigned short Kb[2][64 * 72];   // [kv][d], pad 72
    __shared__ __align__(16) unsigned short Vb[2][64 * 72];   // [d][kv], pad 72
    const int tid = threadIdx.x;
    const int wave = tid >> 6, lane = tid & 63;
    const int m16 = lane & 15, quad = lane >> 4;
    const int qtile = blockIdx.x, bh = blockIdx.y;
    const int b = bh >> 2, h = bh & 3;

    // Q: 64 rows/wave
    bf16x8 qf[4][2];
    const size_t qrow0 = (size_t)b * 4096 + qtile * 256 + wave * 64;
#pragma unroll
    for (int qh = 0; qh < 4; qh++) {
        const unsigned short* qp = qbuf + (qrow0 + qh * 16 + m16) * 256 + h * 64 + quad * 8;
        qf[qh][0] = as_bf16x8(*(const u32x4*)qp);
        qf[qh][1] = as_bf16x8(*(const u32x4*)(qp + 32));
    }

    f32x4 o[4][4] = {};
    float lp[4] = {0.f, 0.f, 0.f, 0.f};

    // staging: 256 threads x (2 K rows + 2 V rows) x 16B
    const int sr = tid >> 3;       // 0..31
    const int sc = tid & 7;        // 16B chunk
    const unsigned short* kg = kbuf + ((size_t)b * 1024) * 256 + h * 64 + sc * 8;
    const unsigned short* vg = vT + ((size_t)bh * 64) * 1024 + sc * 8;

    u32x4 s0 = *(const u32x4*)(kg + (size_t)sr * 256);
    u32x4 s1 = *(const u32x4*)(kg + (size_t)(sr + 32) * 256);
    u32x4 s2 = *(const u32x4*)(vg + (size_t)sr * 1024);
    u32x4 s3 = *(const u32x4*)(vg + (size_t)(sr + 32) * 1024);
    *(u32x4*)&Kb[0][sr * 72 + sc * 8] = s0;
    *(u32x4*)&Kb[0][(sr + 32) * 72 + sc * 8] = s1;
    *(u32x4*)&Vb[0][sr * 72 + sc * 8] = s2;
    *(u32x4*)&Vb[0][(sr + 32) * 72 + sc * 8] = s3;

    for (int it = 0; it < 16; ++it) {
        const int cur = it & 1, nxt = cur ^ 1;
        __syncthreads();
        if (it + 1 < 16) {
            const size_t kvb = (size_t)(it + 1) * 64;
            s0 = *(const u32x4*)(kg + (kvb + sr) * 256);
            s1 = *(const u32x4*)(kg + (kvb + sr + 32) * 256);
            s2 = *(const u32x4*)(vg + kvb + (size_t)sr * 1024);
            s3 = *(const u32x4*)(vg + kvb + (size_t)(sr + 32) * 1024);
        }

#pragma unroll
        for (int mt = 0; mt < 4; mt++) {
            // S^T = K Q^T : C col = q = m16, row = kv = mt*16 + quad*4 + r
            const unsigned short* kp = &Kb[cur][(mt * 16 + m16) * 72 + quad * 8];
            const bf16x8 kf0 = as_bf16x8(*(const u32x4*)kp);
            const bf16x8 kf1 = as_bf16x8(*(const u32x4*)(kp + 32));
            f32x4 st[4];
#pragma unroll
            for (int qh = 0; qh < 4; qh++) {
                f32x4 z = {};
                z = __builtin_amdgcn_mfma_f32_16x16x32_bf16(kf0, qf[qh][0], z, 0, 0, 0);
                st[qh] = __builtin_amdgcn_mfma_f32_16x16x32_bf16(kf1, qf[qh][1], z, 0, 0, 0);
            }
            // P = exp(S*scale); packed P is directly the K=16 MFMA A-frag
            i16x4 pa[4];
#pragma unroll
            for (int qh = 0; qh < 4; qh++) {
                float p0 = __expf(st[qh][0] * 0.125f);
                float p1 = __expf(st[qh][1] * 0.125f);
                float p2 = __expf(st[qh][2] * 0.125f);
                float p3 = __expf(st[qh][3] * 0.125f);
                lp[qh] += (p0 + p1) + (p2 + p3);
                u16x4 pk = { f2bf(p0), f2bf(p1), f2bf(p2), f2bf(p3) };
                pa[qh] = __builtin_bit_cast(i16x4, pk);
            }
            // O += P_chunk V_chunk  (K=16 MFMA, B-frag = V^T[d][mt*16 + quad*4 + j])
#pragma unroll
            for (int nt = 0; nt < 4; nt++) {
                const i16x4 vb = *(const i16x4*)&Vb[cur][(nt * 16 + m16) * 72 + mt * 16 + quad * 4];
#pragma unroll
                for (int qh = 0; qh < 4; qh++)
                    o[qh][nt] = __builtin_amdgcn_mfma_f32_16x16x16bf16_1k(pa[qh], vb, o[qh][nt], 0, 0, 0);
            }
        }

        if (it + 1 < 16) {
            *(u32x4*)&Kb[nxt][sr * 72 + sc * 8] = s0;
            *(u32x4*)&Kb[nxt][(sr + 32) * 72 + sc * 8] = s1;
            *(u32x4*)&Vb[nxt][sr * 72 + sc * 8] = s2;
            *(u32x4*)&Vb[nxt][(sr + 32) * 72 + sc * 8] = s3;
        }
    }

#pragma unroll
    for (int qh = 0; qh < 4; qh++) {
        float l = lp[qh];
        l += __shfl_xor(l, 16);
        l += __shfl_xor(l, 32);
        f32x4 linv;
#pragma unroll
        for (int r = 0; r < 4; r++)
            linv[r] = __builtin_amdgcn_rcpf(__shfl(l, quad * 4 + r));
#pragma unroll
        for (int nt = 0; nt < 4; nt++)
#pragma unroll
            for (int r = 0; r < 4; r++)
                aout[(qrow0 + qh * 16 + quad * 4 + r) * 256 + h * 64 + nt * 16 + m16] =
                    f2bf(o[qh][nt][r] * linv[r]);
    }
}

// ---------------- launcher ----------------

extern "C" void kernel_launch(void* const* d_in, const int* in_sizes, int n_in,
                              void* d_out, int out_size, void* d_ws, size_t ws_size,
                              hipStream_t stream) {
    (void)in_sizes; (void)n_in; (void)out_size; (void)ws_size;
    const float* x        = (const float*)d_in[0];
    const float* l_q_w    = (const float*)d_in[2];
    const float* l_kv_w   = (const float*)d_in[3];
    const float* l_proj_w = (const float*)d_in[4];
    const float* l_proj_b = (const float*)d_in[5];
    const float* h_qkv_w  = (const float*)d_in[6];
    const float* h_proj_w = (const float*)d_in[7];
    const float* h_proj_b = (const float*)d_in[8];
    float* out = (float*)d_out;

    char* ws = (char*)d_ws;
    unsigned short* xb     = (unsigned short*)(ws);             // 33.5MB, dead after mm512
    unsigned short* aout   = (unsigned short*)(ws);             // 16.8MB, overlays xb
    unsigned short* dbuf   = (unsigned short*)(ws + 33554432);  // 16.8MB
    unsigned short* qbuf   = (unsigned short*)(ws + 50331648);  // 16.8MB
    unsigned short* kbuf   = (unsigned short*)(ws + 67108864);  // 4.2MB
    unsigned short* vT     = (unsigned short*)(ws + 71303168);  // 4.2MB
    unsigned short* xpb    = (unsigned short*)(ws + 75497472);  // 8.4MB
    unsigned short* wcatT  = (unsigned short*)(ws + 83886080);
    unsigned short* lkvT   = (unsigned short*)(ws + 84410368);
    unsigned short* hprojT = (unsigned short*)(ws + 84934656);
    unsigned short* lprojT = (unsigned short*)(ws + 85065728);
    // total ws requirement: 85,196,800 B (same as prior rounds)

    // fused cast+pool (2048) + weight transpose (2560)
    k_prep<<<4608, 256, 0, stream>>>(x, h_qkv_w, l_q_w, l_kv_w, h_proj_w, l_proj_w,
                                     xb, xpb, wcatT, lkvT, hprojT, lprojT);
    // gemm1 (1024 blocks) + kv-gemm (256 blocks), fused hifi / V^T epilogues, XCD swizzle
    k_mm512<<<1280, 256, 0, stream>>>(xb, xpb, wcatT, lkvT, dbuf, qbuf, kbuf, vT);
    // attention (aout overlays xb -- xb dead after mm512)
    k_attn<<<dim3(16, 32), 256, 0, stream>>>(qbuf, kbuf, vT, aout);
    // both projections + bias + un-permute into out, XCD swizzle
    k_mmproj<<<1024, 256, 0, stream>>>(dbuf, aout, hprojT, lprojT, h_proj_b, l_proj_b, out);
}

// Round 7
// 226.279 us; speedup vs baseline: 2.2109x; 1.0299x over previous
//
#include <hip/hip_runtime.h>

typedef __bf16 bf16x8 __attribute__((ext_vector_type(8)));
typedef float  f32x4  __attribute__((ext_vector_type(4)));
typedef unsigned int u32x4 __attribute__((ext_vector_type(4)));
typedef unsigned short u16x8 __attribute__((ext_vector_type(8)));
typedef unsigned short u16x4 __attribute__((ext_vector_type(4)));
typedef short i16x4 __attribute__((ext_vector_type(4)));

__device__ __forceinline__ unsigned short f2bf(float f) {
    return __builtin_bit_cast(unsigned short, (__bf16)f);
}
__device__ __forceinline__ bf16x8 as_bf16x8(u32x4 v) {
    return __builtin_bit_cast(bf16x8, v);
}

#define AS1 __attribute__((address_space(1)))
#define AS3 __attribute__((address_space(3)))
__device__ __forceinline__ void gload_lds16(const void* g, void* l) {
    __builtin_amdgcn_global_load_lds((const AS1 void*)g, (AS3 void*)l, 16, 0, 0);
}

// Window-major permutation: m' groups the 4 members of each 2x2 spatial
// window consecutively. n = b*4096 + hh*64 + ww  ->  m' = (b*1024 +
// (hh>>1)*32 + (ww>>1))*4 + (hh&1)*2 + (ww&1).

// ---------------- prep: fused cast+permute+pool (one x read), weight transpose ----------------
__global__ __launch_bounds__(256) void k_prep(
        const float* __restrict__ x,
        const float* __restrict__ h_qkv_w, const float* __restrict__ l_q_w,
        const float* __restrict__ l_kv_w, const float* __restrict__ h_proj_w,
        const float* __restrict__ l_proj_w,
        unsigned short* __restrict__ xb, unsigned short* __restrict__ xpb,
        unsigned short* __restrict__ wcatT, unsigned short* __restrict__ lkvT,
        unsigned short* __restrict__ hprojT, unsigned short* __restrict__ lprojT) {
    int blk = blockIdx.x;
    if (blk < 2048) {
        // thread -> (window widx, 8-channel chunk c8). Reads the 4 window rows once:
        // emits 4 xb rows (m'-order: consecutive!) + 1 pooled xpb row. x read once, not twice.
        int t = blk * 256 + threadIdx.x;
        int widx = t >> 6, c8 = (t & 63) << 3;
        int b = widx >> 10, rem = widx & 1023;
        int h2 = rem >> 5, w2 = rem & 31;
        const float* base = x + ((size_t)(b << 12) + (h2 << 7) + (w2 << 1)) * 512 + c8;
        f32x4 acc0 = {}, acc1 = {};
        const int roff[4] = {0, 1, 64, 65};   // (dh,dw) = (0,0),(0,1),(1,0),(1,1)
#pragma unroll
        for (int j = 0; j < 4; j++) {
            const float* src = base + (size_t)roff[j] * 512;
            f32x4 v0 = *(const f32x4*)src;
            f32x4 v1 = *(const f32x4*)(src + 4);
            acc0 += v0; acc1 += v1;
            u16x8 o = { f2bf(v0[0]), f2bf(v0[1]), f2bf(v0[2]), f2bf(v0[3]),
                        f2bf(v1[0]), f2bf(v1[1]), f2bf(v1[2]), f2bf(v1[3]) };
            *(u16x8*)(xb + ((size_t)widx * 4 + j) * 512 + c8) = o;
        }
        acc0 *= 0.25f; acc1 *= 0.25f;
        u16x8 p = { f2bf(acc0[0]), f2bf(acc0[1]), f2bf(acc0[2]), f2bf(acc0[3]),
                    f2bf(acc1[0]), f2bf(acc1[1]), f2bf(acc1[2]), f2bf(acc1[3]) };
        *(u16x8*)(xpb + (size_t)widx * 512 + c8) = p;
    } else {
        // weights -> B^T bf16
        int i = (blk - 2048) * 256 + threadIdx.x;
        if (i < 262144) {
            int n = i >> 9, k = i & 511;
            float v = (n < 256) ? h_qkv_w[k * 256 + n] : l_q_w[k * 256 + (n - 256)];
            wcatT[i] = f2bf(v);
        } else if (i < 524288) {
            int j = i - 262144; int n = j >> 9, k = j & 511;
            lkvT[j] = f2bf(l_kv_w[k * 512 + n]);
        } else if (i < 589824) {
            int j = i - 524288; int n = j >> 8, k = j & 255;
            hprojT[j] = f2bf(h_proj_w[k * 256 + n]);
        } else {
            int j = i - 589824; int n = j >> 8, k = j & 255;
            lprojT[j] = f2bf(l_proj_w[k * 256 + n]);
        }
    }
}

// ---------------- shared GEMM core: 128x128 tile, BK=32 (m97 structure) ----------------
__device__ __forceinline__ void mm_core(
        const unsigned short* __restrict__ A, const unsigned short* __restrict__ Bt,
        size_t row0, int col0, int K,
        unsigned short* As, unsigned short* Bs, f32x4 (&acc)[4][4]) {
    const int tid = threadIdx.x;
    const int wave = tid >> 6, lane = tid & 63;
    const int m16 = lane & 15, quad = lane >> 4;
    const int wr = wave >> 1, wc = wave & 1;
    const int srow = lane >> 2;
    const int scol = (lane & 3) * 8;
    const unsigned short* Ap0 = A + (row0 + wave * 32 + srow) * (size_t)K + scol;
    const unsigned short* Ap1 = Ap0 + (size_t)16 * K;
    const unsigned short* Bp0 = Bt + (size_t)(col0 + wave * 32 + srow) * K + scol;
    const unsigned short* Bp1 = Bp0 + (size_t)16 * K;
    unsigned short* Al0 = As + wave * 1024;
    unsigned short* Al1 = As + wave * 1024 + 512;
    unsigned short* Bl0 = Bs + wave * 1024;
    unsigned short* Bl1 = Bs + wave * 1024 + 512;

    for (int k0 = 0; k0 < K; k0 += 32) {
        __syncthreads();
        gload_lds16(Ap0 + k0, Al0);
        gload_lds16(Ap1 + k0, Al1);
        gload_lds16(Bp0 + k0, Bl0);
        gload_lds16(Bp1 + k0, Bl1);
        __syncthreads();
        bf16x8 af[4], bfr[4];
#pragma unroll
        for (int mi = 0; mi < 4; mi++)
            af[mi] = as_bf16x8(*(const u32x4*)(As + (wr * 64 + mi * 16 + m16) * 32 + quad * 8));
#pragma unroll
        for (int ni = 0; ni < 4; ni++)
            bfr[ni] = as_bf16x8(*(const u32x4*)(Bs + (wc * 64 + ni * 16 + m16) * 32 + quad * 8));
#pragma unroll
        for (int mi = 0; mi < 4; mi++)
#pragma unroll
            for (int ni = 0; ni < 4; ni++)
                acc[mi][ni] = __builtin_amdgcn_mfma_f32_16x16x32_bf16(af[mi], bfr[ni], acc[mi][ni], 0, 0, 0);
    }
}

// ---------------- launch 2: gemm1 (x@[hqkv|lq] + fused hifi) and kv-gemm (+fused V^T) ----------------
// XCD-chunked swizzle: consecutive original flat ids (= same A row-stripe, different
// col tile) are placed on the SAME XCD so the stripe is fetched into one L2 once.
__global__ __launch_bounds__(256, 2) void k_mm512(
        const unsigned short* __restrict__ xb, const unsigned short* __restrict__ xpb,
        const unsigned short* __restrict__ wcatT, const unsigned short* __restrict__ lkvT,
        unsigned short* __restrict__ dbuf, unsigned short* __restrict__ qbuf,
        unsigned short* __restrict__ kbuf, unsigned short* __restrict__ vT) {
    __shared__ __align__(16) unsigned short As[128 * 32];
    __shared__ __align__(16) unsigned short Bs[128 * 32];
    const int bid = blockIdx.x;                       // 0..1279, 1280%8==0 -> bijective
    const int flat = (bid & 7) * 160 + (bid >> 3);
    const bool isg1 = flat < 1024;
    const unsigned short* A;
    const unsigned short* Bt;
    size_t row0; int col0;
    if (isg1) { A = xb;  Bt = wcatT; row0 = (size_t)(flat >> 2) * 128; col0 = (flat & 3) * 128; }
    else { int f = flat - 1024; A = xpb; Bt = lkvT; row0 = (size_t)(f >> 2) * 128; col0 = (f & 3) * 128; }

    f32x4 acc[4][4] = {};
    mm_core(A, Bt, row0, col0, 512, As, Bs, acc);

    const int tid = threadIdx.x;
    const int wave = tid >> 6, lane = tid & 63;
    const int m16 = lane & 15, quad = lane >> 4;
    const int wr = wave >> 1, wc = wave & 1;

    if (isg1) {
        if (col0 < 256) {
            // hifi: lane's 4 rows are one 2x2 window (m'-order) -> dbuf = mean - val
#pragma unroll
            for (int mi = 0; mi < 4; mi++)
#pragma unroll
                for (int ni = 0; ni < 4; ni++) {
                    const int col = col0 + wc * 64 + ni * 16 + m16;
                    const size_t mb = row0 + wr * 64 + mi * 16 + quad * 4;
                    float v0 = acc[mi][ni][0], v1 = acc[mi][ni][1];
                    float v2 = acc[mi][ni][2], v3 = acc[mi][ni][3];
                    float m = 0.25f * ((v0 + v1) + (v2 + v3));
                    dbuf[(mb + 0) * 256 + col] = f2bf(m - v0);
                    dbuf[(mb + 1) * 256 + col] = f2bf(m - v1);
                    dbuf[(mb + 2) * 256 + col] = f2bf(m - v2);
                    dbuf[(mb + 3) * 256 + col] = f2bf(m - v3);
                }
        } else {
            // Q (unscaled -- R5 lesson: softmax scale stays in k_attn's __expf, whose
            // v_mul co-issues for free; __builtin_exp2f's denormal-guard lowering cost
            // ~14us of serial VALU)
#pragma unroll
            for (int mi = 0; mi < 4; mi++)
#pragma unroll
                for (int ni = 0; ni < 4; ni++) {
                    const int col = col0 - 256 + wc * 64 + ni * 16 + m16;
                    const size_t mb = row0 + wr * 64 + mi * 16 + quad * 4;
#pragma unroll
                    for (int r = 0; r < 4; r++)
                        qbuf[(mb + r) * 256 + col] = f2bf(acc[mi][ni][r]);
                }
        }
    } else {
        if (col0 < 256) {
#pragma unroll
            for (int mi = 0; mi < 4; mi++)
#pragma unroll
                for (int ni = 0; ni < 4; ni++) {
                    const int col = col0 + wc * 64 + ni * 16 + m16;
                    const size_t row = row0 + wr * 64 + mi * 16 + quad * 4;
#pragma unroll
                    for (int r = 0; r < 4; r++)
                        kbuf[(row + r) * 256 + col] = f2bf(acc[mi][ni][r]);
                }
        } else {
            // V stored transposed: vT[(b*4+h)*64 + d][kv], lane's 4 rows = 4 consecutive kv
#pragma unroll
            for (int mi = 0; mi < 4; mi++)
#pragma unroll
                for (int ni = 0; ni < 4; ni++) {
                    const int d = col0 - 256 + wc * 64 + ni * 16 + m16;
                    const int hh = d >> 6, dd = d & 63;
                    const size_t kvg = row0 + wr * 64 + mi * 16 + quad * 4;
                    const int b = (int)(kvg >> 10), kv = (int)(kvg & 1023);
                    u16x4 pk = { f2bf(acc[mi][ni][0]), f2bf(acc[mi][ni][1]),
                                 f2bf(acc[mi][ni][2]), f2bf(acc[mi][ni][3]) };
                    *(u16x4*)(vT + (((size_t)(b * 4 + hh) * 64 + dd) << 10) + kv) = pk;
                }
        }
    }
}

// ---------------- launch 4: both projection GEMMs, un-permuting epilogue ----------------
__global__ __launch_bounds__(256, 2) void k_mmproj(
        const unsigned short* __restrict__ dbuf, const unsigned short* __restrict__ aout,
        const unsigned short* __restrict__ hprojT, const unsigned short* __restrict__ lprojT,
        const float* __restrict__ h_proj_b, const float* __restrict__ l_proj_b,
        float* __restrict__ out) {
    __shared__ __align__(16) unsigned short As[128 * 32];
    __shared__ __align__(16) unsigned short Bs[128 * 32];
    const int bid = blockIdx.x;                       // 0..1023, 1024%8==0 -> bijective
    const int flat = (bid & 7) * 128 + (bid >> 3);
    const bool hi = flat < 512;
    const int f = flat & 511;
    const unsigned short* A  = hi ? dbuf : aout;
    const unsigned short* Bt = hi ? hprojT : lprojT;
    const float* bias = hi ? h_proj_b : l_proj_b;
    const int coloff = hi ? 0 : 256;
    const size_t row0 = (size_t)(f >> 1) * 128;
    const int col0 = (f & 1) * 128;

    f32x4 acc[4][4] = {};
    mm_core(A, Bt, row0, col0, 256, As, Bs, acc);

    const int tid = threadIdx.x;
    const int wave = tid >> 6, lane = tid & 63;
    const int m16 = lane & 15, quad = lane >> 4;
    const int wr = wave >> 1, wc = wave & 1;

#pragma unroll
    for (int mi = 0; mi < 4; mi++)
#pragma unroll
        for (int ni = 0; ni < 4; ni++) {
            const int col = col0 + wc * 64 + ni * 16 + m16;
            const float bv = bias[col];
            const size_t mb = row0 + wr * 64 + mi * 16 + quad * 4;
            const int widx = (int)(mb >> 2);
            const int b = widx >> 10, rem = widx & 1023;
            const int h2 = rem >> 5, w2 = rem & 31;
            const size_t nb = ((size_t)b << 12) + (h2 << 7) + (w2 << 1);
            float* op = out + nb * 512 + coloff + col;
            op[0]            = acc[mi][ni][0] + bv;
            op[512]          = acc[mi][ni][1] + bv;
            op[64 * 512]     = acc[mi][ni][2] + bv;
            op[65 * 512]     = acc[mi][ni][3] + bv;
        }
}

// ---------------- fused lo-fi attention: 4 waves x 64 q rows, no P round-trip ----------------
// Round-0 structure (55.2us): 256 thr, (256,2), __expf(st*0.125f) -- the v_mul co-issues;
// do NOT replace with __builtin_exp2f (R5: denormal-guard lowering, +14us VALU).
// Do NOT touch __launch_bounds__ (R2/R4: min-waves>=4 clamps VGPR to 64 -> spill).
// S^T = K Q^T (16x16x32) leaves P[q=m16][kv=quad*4+r] in registers -- exactly the
// A-fragment layout of v_mfma_f32_16x16x16bf16_1k. PV consumes P directly from regs.
// This round's single change: softmax denominator on the MFMA pipe -- one extra
// PV-style MFMA per (mt,qh) with B = all-ones bf16 yields l[q] in D rows quad*4+r
// (verified correct in R3). Removes 16 VALU adds/mt + the 24-shuffle epilogue
// reduction from the critical VALU pipe (51% busy vs MFMA 37%). NO setprio (R3).
__global__ __launch_bounds__(256, 2) void k_attn(
        const unsigned short* __restrict__ qbuf,  // [32768,256] m'-order
        const unsigned short* __restrict__ kbuf,  // [8192,256]
        const unsigned short* __restrict__ vT,    // [32][64][1024]
        unsigned short* __restrict__ aout) {      // [32768,256] m'-order
    __shared__ __align__(16) unsigned short Kb[2][64 * 72];   // [kv][d], pad 72
    __shared__ __align__(16) unsigned short Vb[2][64 * 72];   // [d][kv], pad 72
    const int tid = threadIdx.x;
    const int wave = tid >> 6, lane = tid & 63;
    const int m16 = lane & 15, quad = lane >> 4;
    const int qtile = blockIdx.x, bh = blockIdx.y;
    const int b = bh >> 2, h = bh & 3;

    // Q: 64 rows/wave
    bf16x8 qf[4][2];
    const size_t qrow0 = (size_t)b * 4096 + qtile * 256 + wave * 64;
#pragma unroll
    for (int qh = 0; qh < 4; qh++) {
        const unsigned short* qp = qbuf + (qrow0 + qh * 16 + m16) * 256 + h * 64 + quad * 8;
        qf[qh][0] = as_bf16x8(*(const u32x4*)qp);
        qf[qh][1] = as_bf16x8(*(const u32x4*)(qp + 32));
    }

    f32x4 o[4][4] = {};
    f32x4 ol[4] = {};                               // softmax denominators (MFMA-accumulated)
    const i16x4 ones = { 0x3F80, 0x3F80, 0x3F80, 0x3F80 };  // bf16 1.0 x4

    // staging: 256 threads x (2 K rows + 2 V rows) x 16B
    const int sr = tid >> 3;       // 0..31
    const int sc = tid & 7;        // 16B chunk
    const unsigned short* kg = kbuf + ((size_t)b * 1024) * 256 + h * 64 + sc * 8;
    const unsigned short* vg = vT + ((size_t)bh * 64) * 1024 + sc * 8;

    u32x4 s0 = *(const u32x4*)(kg + (size_t)sr * 256);
    u32x4 s1 = *(const u32x4*)(kg + (size_t)(sr + 32) * 256);
    u32x4 s2 = *(const u32x4*)(vg + (size_t)sr * 1024);
    u32x4 s3 = *(const u32x4*)(vg + (size_t)(sr + 32) * 1024);
    *(u32x4*)&Kb[0][sr * 72 + sc * 8] = s0;
    *(u32x4*)&Kb[0][(sr + 32) * 72 + sc * 8] = s1;
    *(u32x4*)&Vb[0][sr * 72 + sc * 8] = s2;
    *(u32x4*)&Vb[0][(sr + 32) * 72 + sc * 8] = s3;

    for (int it = 0; it < 16; ++it) {
        const int cur = it & 1, nxt = cur ^ 1;
        __syncthreads();
        if (it + 1 < 16) {
            const size_t kvb = (size_t)(it + 1) * 64;
            s0 = *(const u32x4*)(kg + (kvb + sr) * 256);
            s1 = *(const u32x4*)(kg + (kvb + sr + 32) * 256);
            s2 = *(const u32x4*)(vg + kvb + (size_t)sr * 1024);
            s3 = *(const u32x4*)(vg + kvb + (size_t)(sr + 32) * 1024);
        }

#pragma unroll
        for (int mt = 0; mt < 4; mt++) {
            // S^T = K Q^T : C col = q = m16, row = kv = mt*16 + quad*4 + r
            const unsigned short* kp = &Kb[cur][(mt * 16 + m16) * 72 + quad * 8];
            const bf16x8 kf0 = as_bf16x8(*(const u32x4*)kp);
            const bf16x8 kf1 = as_bf16x8(*(const u32x4*)(kp + 32));
            f32x4 st[4];
#pragma unroll
            for (int qh = 0; qh < 4; qh++) {
                f32x4 z = {};
                z = __builtin_amdgcn_mfma_f32_16x16x32_bf16(kf0, qf[qh][0], z, 0, 0, 0);
                st[qh] = __builtin_amdgcn_mfma_f32_16x16x32_bf16(kf1, qf[qh][1], z, 0, 0, 0);
            }
            // P = exp(S*scale); packed P is directly the K=16 MFMA A-frag
            i16x4 pa[4];
#pragma unroll
            for (int qh = 0; qh < 4; qh++) {
                float p0 = __expf(st[qh][0] * 0.125f);
                float p1 = __expf(st[qh][1] * 0.125f);
                float p2 = __expf(st[qh][2] * 0.125f);
                float p3 = __expf(st[qh][3] * 0.125f);
                u16x4 pk = { f2bf(p0), f2bf(p1), f2bf(p2), f2bf(p3) };
                pa[qh] = __builtin_bit_cast(i16x4, pk);
            }
            // O += P_chunk V_chunk; l += P_chunk @ ones (denominator on the MFMA pipe)
#pragma unroll
            for (int nt = 0; nt < 4; nt++) {
                const i16x4 vb = *(const i16x4*)&Vb[cur][(nt * 16 + m16) * 72 + mt * 16 + quad * 4];
#pragma unroll
                for (int qh = 0; qh < 4; qh++)
                    o[qh][nt] = __builtin_amdgcn_mfma_f32_16x16x16bf16_1k(pa[qh], vb, o[qh][nt], 0, 0, 0);
            }
#pragma unroll
            for (int qh = 0; qh < 4; qh++)
                ol[qh] = __builtin_amdgcn_mfma_f32_16x16x16bf16_1k(pa[qh], ones, ol[qh], 0, 0, 0);
        }

        if (it + 1 < 16) {
            *(u32x4*)&Kb[nxt][sr * 72 + sc * 8] = s0;
            *(u32x4*)&Kb[nxt][(sr + 32) * 72 + sc * 8] = s1;
            *(u32x4*)&Vb[nxt][sr * 72 + sc * 8] = s2;
            *(u32x4*)&Vb[nxt][(sr + 32) * 72 + sc * 8] = s3;
        }
    }

    // ol[qh][r] = l for q-row quad*4+r (all d-columns identical) -- no shuffles needed
#pragma unroll
    for (int qh = 0; qh < 4; qh++) {
        f32x4 linv;
#pragma unroll
        for (int r = 0; r < 4; r++)
            linv[r] = __builtin_amdgcn_rcpf(ol[qh][r]);
#pragma unroll
        for (int nt = 0; nt < 4; nt++)
#pragma unroll
            for (int r = 0; r < 4; r++)
                aout[(qrow0 + qh * 16 + quad * 4 + r) * 256 + h * 64 + nt * 16 + m16] =
                    f2bf(o[qh][nt][r] * linv[r]);
    }
}

// ---------------- launcher ----------------

extern "C" void kernel_launch(void* const* d_in, const int* in_sizes, int n_in,
                              void* d_out, int out_size, void* d_ws, size_t ws_size,
                              hipStream_t stream) {
    (void)in_sizes; (void)n_in; (void)out_size; (void)ws_size;
    const float* x        = (const float*)d_in[0];
    const float* l_q_w    = (const float*)d_in[2];
    const float* l_kv_w   = (const float*)d_in[3];
    const float* l_proj_w = (const float*)d_in[4];
    const float* l_proj_b = (const float*)d_in[5];
    const float* h_qkv_w  = (const float*)d_in[6];
    const float* h_proj_w = (const float*)d_in[7];
    const float* h_proj_b = (const float*)d_in[8];
    float* out = (float*)d_out;

    char* ws = (char*)d_ws;
    unsigned short* xb     = (unsigned short*)(ws);             // 33.5MB, dead after mm512
    unsigned short* aout   = (unsigned short*)(ws);             // 16.8MB, overlays xb
    unsigned short* dbuf   = (unsigned short*)(ws + 33554432);  // 16.8MB
    unsigned short* qbuf   = (unsigned short*)(ws + 50331648);  // 16.8MB
    unsigned short* kbuf   = (unsigned short*)(ws + 67108864);  // 4.2MB
    unsigned short* vT     = (unsigned short*)(ws + 71303168);  // 4.2MB
    unsigned short* xpb    = (unsigned short*)(ws + 75497472);  // 8.4MB
    unsigned short* wcatT  = (unsigned short*)(ws + 83886080);
    unsigned short* lkvT   = (unsigned short*)(ws + 84410368);
    unsigned short* hprojT = (unsigned short*)(ws + 84934656);
    unsigned short* lprojT = (unsigned short*)(ws + 85065728);
    // total ws requirement: 85,196,800 B (same as prior rounds)

    // fused cast+pool (2048) + weight transpose (2560)
    k_prep<<<4608, 256, 0, stream>>>(x, h_qkv_w, l_q_w, l_kv_w, h_proj_w, l_proj_w,
                                     xb, xpb, wcatT, lkvT, hprojT, lprojT);
    // gemm1 (1024 blocks) + kv-gemm (256 blocks), fused hifi / V^T epilogues, XCD swizzle
    k_mm512<<<1280, 256, 0, stream>>>(xb, xpb, wcatT, lkvT, dbuf, qbuf, kbuf, vT);
    // attention (aout overlays xb -- xb dead after mm512)
    k_attn<<<dim3(16, 32), 256, 0, stream>>>(qbuf, kbuf, vT, aout);
    // both projections + bias + un-permute into out, XCD swizzle
    k_mmproj<<<1024, 256, 0, stream>>>(dbuf, aout, hprojT, lprojT, h_proj_b, l_proj_b, out);
}

// Round 8
// 225.935 us; speedup vs baseline: 2.2143x; 1.0015x over previous
//
#include <hip/hip_runtime.h>

typedef __bf16 bf16x8 __attribute__((ext_vector_type(8)));
typedef float  f32x4  __attribute__((ext_vector_type(4)));
typedef unsigned int u32x4 __attribute__((ext_vector_type(4)));
typedef unsigned short u16x8 __attribute__((ext_vector_type(8)));
typedef unsigned short u16x4 __attribute__((ext_vector_type(4)));
typedef short i16x4 __attribute__((ext_vector_type(4)));

__device__ __forceinline__ unsigned short f2bf(float f) {
    return __builtin_bit_cast(unsigned short, (__bf16)f);
}
__device__ __forceinline__ bf16x8 as_bf16x8(u32x4 v) {
    return __builtin_bit_cast(bf16x8, v);
}

#define AS1 __attribute__((address_space(1)))
#define AS3 __attribute__((address_space(3)))
__device__ __forceinline__ void gload_lds16(const void* g, void* l) {
    __builtin_amdgcn_global_load_lds((const AS1 void*)g, (AS3 void*)l, 16, 0, 0);
}

// Window-major permutation: m' groups the 4 members of each 2x2 spatial
// window consecutively. n = b*4096 + hh*64 + ww  ->  m' = (b*1024 +
// (hh>>1)*32 + (ww>>1))*4 + (hh&1)*2 + (ww&1).

// ---------------- prep: fused cast+permute+pool (one x read), weight transpose ----------------
__global__ __launch_bounds__(256) void k_prep(
        const float* __restrict__ x,
        const float* __restrict__ h_qkv_w, const float* __restrict__ l_q_w,
        const float* __restrict__ l_kv_w, const float* __restrict__ h_proj_w,
        const float* __restrict__ l_proj_w,
        unsigned short* __restrict__ xb, unsigned short* __restrict__ xpb,
        unsigned short* __restrict__ wcatT, unsigned short* __restrict__ lkvT,
        unsigned short* __restrict__ hprojT, unsigned short* __restrict__ lprojT) {
    int blk = blockIdx.x;
    if (blk < 2048) {
        // thread -> (window widx, 8-channel chunk c8). Reads the 4 window rows once:
        // emits 4 xb rows (m'-order: consecutive!) + 1 pooled xpb row. x read once, not twice.
        int t = blk * 256 + threadIdx.x;
        int widx = t >> 6, c8 = (t & 63) << 3;
        int b = widx >> 10, rem = widx & 1023;
        int h2 = rem >> 5, w2 = rem & 31;
        const float* base = x + ((size_t)(b << 12) + (h2 << 7) + (w2 << 1)) * 512 + c8;
        f32x4 acc0 = {}, acc1 = {};
        const int roff[4] = {0, 1, 64, 65};   // (dh,dw) = (0,0),(0,1),(1,0),(1,1)
#pragma unroll
        for (int j = 0; j < 4; j++) {
            const float* src = base + (size_t)roff[j] * 512;
            f32x4 v0 = *(const f32x4*)src;
            f32x4 v1 = *(const f32x4*)(src + 4);
            acc0 += v0; acc1 += v1;
            u16x8 o = { f2bf(v0[0]), f2bf(v0[1]), f2bf(v0[2]), f2bf(v0[3]),
                        f2bf(v1[0]), f2bf(v1[1]), f2bf(v1[2]), f2bf(v1[3]) };
            *(u16x8*)(xb + ((size_t)widx * 4 + j) * 512 + c8) = o;
        }
        acc0 *= 0.25f; acc1 *= 0.25f;
        u16x8 p = { f2bf(acc0[0]), f2bf(acc0[1]), f2bf(acc0[2]), f2bf(acc0[3]),
                    f2bf(acc1[0]), f2bf(acc1[1]), f2bf(acc1[2]), f2bf(acc1[3]) };
        *(u16x8*)(xpb + (size_t)widx * 512 + c8) = p;
    } else {
        // weights -> B^T bf16
        int i = (blk - 2048) * 256 + threadIdx.x;
        if (i < 262144) {
            int n = i >> 9, k = i & 511;
            float v = (n < 256) ? h_qkv_w[k * 256 + n] : l_q_w[k * 256 + (n - 256)];
            wcatT[i] = f2bf(v);
        } else if (i < 524288) {
            int j = i - 262144; int n = j >> 9, k = j & 511;
            lkvT[j] = f2bf(l_kv_w[k * 512 + n]);
        } else if (i < 589824) {
            int j = i - 524288; int n = j >> 8, k = j & 255;
            hprojT[j] = f2bf(h_proj_w[k * 256 + n]);
        } else {
            int j = i - 589824; int n = j >> 8, k = j & 255;
            lprojT[j] = f2bf(l_proj_w[k * 256 + n]);
        }
    }
}

// ---------------- shared GEMM core: 128x128 tile, BK=32 (m97 structure) ----------------
__device__ __forceinline__ void mm_core(
        const unsigned short* __restrict__ A, const unsigned short* __restrict__ Bt,
        size_t row0, int col0, int K,
        unsigned short* As, unsigned short* Bs, f32x4 (&acc)[4][4]) {
    const int tid = threadIdx.x;
    const int wave = tid >> 6, lane = tid & 63;
    const int m16 = lane & 15, quad = lane >> 4;
    const int wr = wave >> 1, wc = wave & 1;
    const int srow = lane >> 2;
    const int scol = (lane & 3) * 8;
    const unsigned short* Ap0 = A + (row0 + wave * 32 + srow) * (size_t)K + scol;
    const unsigned short* Ap1 = Ap0 + (size_t)16 * K;
    const unsigned short* Bp0 = Bt + (size_t)(col0 + wave * 32 + srow) * K + scol;
    const unsigned short* Bp1 = Bp0 + (size_t)16 * K;
    unsigned short* Al0 = As + wave * 1024;
    unsigned short* Al1 = As + wave * 1024 + 512;
    unsigned short* Bl0 = Bs + wave * 1024;
    unsigned short* Bl1 = Bs + wave * 1024 + 512;

    for (int k0 = 0; k0 < K; k0 += 32) {
        __syncthreads();
        gload_lds16(Ap0 + k0, Al0);
        gload_lds16(Ap1 + k0, Al1);
        gload_lds16(Bp0 + k0, Bl0);
        gload_lds16(Bp1 + k0, Bl1);
        __syncthreads();
        bf16x8 af[4], bfr[4];
#pragma unroll
        for (int mi = 0; mi < 4; mi++)
            af[mi] = as_bf16x8(*(const u32x4*)(As + (wr * 64 + mi * 16 + m16) * 32 + quad * 8));
#pragma unroll
        for (int ni = 0; ni < 4; ni++)
            bfr[ni] = as_bf16x8(*(const u32x4*)(Bs + (wc * 64 + ni * 16 + m16) * 32 + quad * 8));
#pragma unroll
        for (int mi = 0; mi < 4; mi++)
#pragma unroll
            for (int ni = 0; ni < 4; ni++)
                acc[mi][ni] = __builtin_amdgcn_mfma_f32_16x16x32_bf16(af[mi], bfr[ni], acc[mi][ni], 0, 0, 0);
    }
}

// ---------------- launch 2: gemm1 (x@[hqkv|lq] + fused hifi) and kv-gemm (+fused V^T) ----------------
// XCD-chunked swizzle: consecutive original flat ids (= same A row-stripe, different
// col tile) are placed on the SAME XCD so the stripe is fetched into one L2 once.
__global__ __launch_bounds__(256, 2) void k_mm512(
        const unsigned short* __restrict__ xb, const unsigned short* __restrict__ xpb,
        const unsigned short* __restrict__ wcatT, const unsigned short* __restrict__ lkvT,
        unsigned short* __restrict__ dbuf, unsigned short* __restrict__ qbuf,
        unsigned short* __restrict__ kbuf, unsigned short* __restrict__ vT) {
    __shared__ __align__(16) unsigned short As[128 * 32];
    __shared__ __align__(16) unsigned short Bs[128 * 32];
    const int bid = blockIdx.x;                       // 0..1279, 1280%8==0 -> bijective
    const int flat = (bid & 7) * 160 + (bid >> 3);
    const bool isg1 = flat < 1024;
    const unsigned short* A;
    const unsigned short* Bt;
    size_t row0; int col0;
    if (isg1) { A = xb;  Bt = wcatT; row0 = (size_t)(flat >> 2) * 128; col0 = (flat & 3) * 128; }
    else { int f = flat - 1024; A = xpb; Bt = lkvT; row0 = (size_t)(f >> 2) * 128; col0 = (f & 3) * 128; }

    f32x4 acc[4][4] = {};
    mm_core(A, Bt, row0, col0, 512, As, Bs, acc);

    const int tid = threadIdx.x;
    const int wave = tid >> 6, lane = tid & 63;
    const int m16 = lane & 15, quad = lane >> 4;
    const int wr = wave >> 1, wc = wave & 1;

    if (isg1) {
        if (col0 < 256) {
            // hifi: lane's 4 rows are one 2x2 window (m'-order) -> dbuf = mean - val
#pragma unroll
            for (int mi = 0; mi < 4; mi++)
#pragma unroll
                for (int ni = 0; ni < 4; ni++) {
                    const int col = col0 + wc * 64 + ni * 16 + m16;
                    const size_t mb = row0 + wr * 64 + mi * 16 + quad * 4;
                    float v0 = acc[mi][ni][0], v1 = acc[mi][ni][1];
                    float v2 = acc[mi][ni][2], v3 = acc[mi][ni][3];
                    float m = 0.25f * ((v0 + v1) + (v2 + v3));
                    dbuf[(mb + 0) * 256 + col] = f2bf(m - v0);
                    dbuf[(mb + 1) * 256 + col] = f2bf(m - v1);
                    dbuf[(mb + 2) * 256 + col] = f2bf(m - v2);
                    dbuf[(mb + 3) * 256 + col] = f2bf(m - v3);
                }
        } else {
            // Q (unscaled -- R5 lesson: softmax scale stays in k_attn's __expf)
#pragma unroll
            for (int mi = 0; mi < 4; mi++)
#pragma unroll
                for (int ni = 0; ni < 4; ni++) {
                    const int col = col0 - 256 + wc * 64 + ni * 16 + m16;
                    const size_t mb = row0 + wr * 64 + mi * 16 + quad * 4;
#pragma unroll
                    for (int r = 0; r < 4; r++)
                        qbuf[(mb + r) * 256 + col] = f2bf(acc[mi][ni][r]);
                }
        }
    } else {
        if (col0 < 256) {
#pragma unroll
            for (int mi = 0; mi < 4; mi++)
#pragma unroll
                for (int ni = 0; ni < 4; ni++) {
                    const int col = col0 + wc * 64 + ni * 16 + m16;
                    const size_t row = row0 + wr * 64 + mi * 16 + quad * 4;
#pragma unroll
                    for (int r = 0; r < 4; r++)
                        kbuf[(row + r) * 256 + col] = f2bf(acc[mi][ni][r]);
                }
        } else {
            // V stored transposed: vT[(b*4+h)*64 + d][kv], lane's 4 rows = 4 consecutive kv
#pragma unroll
            for (int mi = 0; mi < 4; mi++)
#pragma unroll
                for (int ni = 0; ni < 4; ni++) {
                    const int d = col0 - 256 + wc * 64 + ni * 16 + m16;
                    const int hh = d >> 6, dd = d & 63;
                    const size_t kvg = row0 + wr * 64 + mi * 16 + quad * 4;
                    const int b = (int)(kvg >> 10), kv = (int)(kvg & 1023);
                    u16x4 pk = { f2bf(acc[mi][ni][0]), f2bf(acc[mi][ni][1]),
                                 f2bf(acc[mi][ni][2]), f2bf(acc[mi][ni][3]) };
                    *(u16x4*)(vT + (((size_t)(b * 4 + hh) * 64 + dd) << 10) + kv) = pk;
                }
        }
    }
}

// ---------------- launch 3: attention (blocks 0..511) + hi-fi projection (512..1023) ----
// R2 retry with the ACTUAL bug fixed: launch bounds (256,2) -- NOT (256,4), which clamps
// VGPR to 64 and spills (R2/R4). Resources (124 VGPR -> 4 waves/SIMD = 496<=512; LDS
// 36.9KB -> 4 blocks/CU = 147<=160KB) allow 4 blocks/CU; attn alone is grid-limited to
// 2. With 1024 blocks each CU holds ~2 attn + ~2 hiproj blocks CONCURRENTLY: hiproj's
// HBM/MFMA work fills pipes attn leaves idle (attn: HBM 13%, MFMA 37%, issue-bound).
// Attn path = R6 proven body byte-for-byte (expf, lp on VALU, no ones-MFMA (R7: +7us),
// no setprio (R3)).
__global__ __launch_bounds__(256, 2) void k_attn_hiproj(
        const unsigned short* __restrict__ qbuf,  // [32768,256] m'-order
        const unsigned short* __restrict__ kbuf,  // [8192,256]
        const unsigned short* __restrict__ vT,    // [32][64][1024]
        unsigned short* __restrict__ aout,        // [32768,256] m'-order
        const unsigned short* __restrict__ dbuf,  // [32768,256] m'-order
        const unsigned short* __restrict__ hprojT,
        const float* __restrict__ h_proj_b,
        float* __restrict__ out) {
    __shared__ __align__(16) unsigned short smem[4 * 64 * 72];  // 36,864 B union
    const int bx = blockIdx.x;
    const int tid = threadIdx.x;
    const int wave = tid >> 6, lane = tid & 63;
    const int m16 = lane & 15, quad = lane >> 4;

    if (bx < 512) {
        // ---------------- attention (R6 body) ----------------
        unsigned short* Kb = smem;                 // [2][64*72]
        unsigned short* Vb = smem + 2 * 64 * 72;   // [2][64*72]
        const int qtile = bx & 15, bh = bx >> 4;
        const int b = bh >> 2, h = bh & 3;

        bf16x8 qf[4][2];
        const size_t qrow0 = (size_t)b * 4096 + qtile * 256 + wave * 64;
#pragma unroll
        for (int qh = 0; qh < 4; qh++) {
            const unsigned short* qp = qbuf + (qrow0 + qh * 16 + m16) * 256 + h * 64 + quad * 8;
            qf[qh][0] = as_bf16x8(*(const u32x4*)qp);
            qf[qh][1] = as_bf16x8(*(const u32x4*)(qp + 32));
        }

        f32x4 o[4][4] = {};
        float lp[4] = {0.f, 0.f, 0.f, 0.f};

        const int sr = tid >> 3;       // 0..31
        const int sc = tid & 7;        // 16B chunk
        const unsigned short* kg = kbuf + ((size_t)b * 1024) * 256 + h * 64 + sc * 8;
        const unsigned short* vg = vT + ((size_t)bh * 64) * 1024 + sc * 8;

        u32x4 s0 = *(const u32x4*)(kg + (size_t)sr * 256);
        u32x4 s1 = *(const u32x4*)(kg + (size_t)(sr + 32) * 256);
        u32x4 s2 = *(const u32x4*)(vg + (size_t)sr * 1024);
        u32x4 s3 = *(const u32x4*)(vg + (size_t)(sr + 32) * 1024);
        *(u32x4*)&Kb[sr * 72 + sc * 8] = s0;
        *(u32x4*)&Kb[(sr + 32) * 72 + sc * 8] = s1;
        *(u32x4*)&Vb[sr * 72 + sc * 8] = s2;
        *(u32x4*)&Vb[(sr + 32) * 72 + sc * 8] = s3;

        for (int it = 0; it < 16; ++it) {
            const int cur = (it & 1) * 4608, nxt = cur ^ 4608;
            __syncthreads();
            if (it + 1 < 16) {
                const size_t kvb = (size_t)(it + 1) * 64;
                s0 = *(const u32x4*)(kg + (kvb + sr) * 256);
                s1 = *(const u32x4*)(kg + (kvb + sr + 32) * 256);
                s2 = *(const u32x4*)(vg + kvb + (size_t)sr * 1024);
                s3 = *(const u32x4*)(vg + kvb + (size_t)(sr + 32) * 1024);
            }

#pragma unroll
            for (int mt = 0; mt < 4; mt++) {
                // S^T = K Q^T : C col = q = m16, row = kv = mt*16 + quad*4 + r
                const unsigned short* kp = &Kb[cur + (mt * 16 + m16) * 72 + quad * 8];
                const bf16x8 kf0 = as_bf16x8(*(const u32x4*)kp);
                const bf16x8 kf1 = as_bf16x8(*(const u32x4*)(kp + 32));
                f32x4 st[4];
#pragma unroll
                for (int qh = 0; qh < 4; qh++) {
                    f32x4 z = {};
                    z = __builtin_amdgcn_mfma_f32_16x16x32_bf16(kf0, qf[qh][0], z, 0, 0, 0);
                    st[qh] = __builtin_amdgcn_mfma_f32_16x16x32_bf16(kf1, qf[qh][1], z, 0, 0, 0);
                }
                // P = exp(S*scale); packed P is directly the K=16 MFMA A-frag
                i16x4 pa[4];
#pragma unroll
                for (int qh = 0; qh < 4; qh++) {
                    float p0 = __expf(st[qh][0] * 0.125f);
                    float p1 = __expf(st[qh][1] * 0.125f);
                    float p2 = __expf(st[qh][2] * 0.125f);
                    float p3 = __expf(st[qh][3] * 0.125f);
                    lp[qh] += (p0 + p1) + (p2 + p3);
                    u16x4 pk = { f2bf(p0), f2bf(p1), f2bf(p2), f2bf(p3) };
                    pa[qh] = __builtin_bit_cast(i16x4, pk);
                }
#pragma unroll
                for (int nt = 0; nt < 4; nt++) {
                    const i16x4 vb = *(const i16x4*)&Vb[cur + (nt * 16 + m16) * 72 + mt * 16 + quad * 4];
#pragma unroll
                    for (int qh = 0; qh < 4; qh++)
                        o[qh][nt] = __builtin_amdgcn_mfma_f32_16x16x16bf16_1k(pa[qh], vb, o[qh][nt], 0, 0, 0);
                }
            }

            if (it + 1 < 16) {
                *(u32x4*)&Kb[nxt + sr * 72 + sc * 8] = s0;
                *(u32x4*)&Kb[nxt + (sr + 32) * 72 + sc * 8] = s1;
                *(u32x4*)&Vb[nxt + sr * 72 + sc * 8] = s2;
                *(u32x4*)&Vb[nxt + (sr + 32) * 72 + sc * 8] = s3;
            }
        }

#pragma unroll
        for (int qh = 0; qh < 4; qh++) {
            float l = lp[qh];
            l += __shfl_xor(l, 16);
            l += __shfl_xor(l, 32);
            f32x4 linv;
#pragma unroll
            for (int r = 0; r < 4; r++)
                linv[r] = __builtin_amdgcn_rcpf(__shfl(l, quad * 4 + r));
#pragma unroll
            for (int nt = 0; nt < 4; nt++)
#pragma unroll
                for (int r = 0; r < 4; r++)
                    aout[(qrow0 + qh * 16 + quad * 4 + r) * 256 + h * 64 + nt * 16 + m16] =
                        f2bf(o[qh][nt][r] * linv[r]);
        }
    } else {
        // ---------------- hi-fi projection GEMM (R2 proven-correct epilogue) ----------------
        unsigned short* As = smem;
        unsigned short* Bs = smem + 128 * 32;
        const int f = bx - 512;                    // 0..511
        const size_t row0 = (size_t)(f >> 1) * 128;
        const int col0 = (f & 1) * 128;

        f32x4 acc[4][4] = {};
        mm_core(dbuf, hprojT, row0, col0, 256, As, Bs, acc);

        const int wr = wave >> 1, wc = wave & 1;
#pragma unroll
        for (int mi = 0; mi < 4; mi++)
#pragma unroll
            for (int ni = 0; ni < 4; ni++) {
                const int col = col0 + wc * 64 + ni * 16 + m16;
                const float bv = h_proj_b[col];
                const size_t mb = row0 + wr * 64 + mi * 16 + quad * 4;
                const int widx = (int)(mb >> 2);
                const int b = widx >> 10, rem = widx & 1023;
                const int h2 = rem >> 5, w2 = rem & 31;
                const size_t nb = ((size_t)b << 12) + (h2 << 7) + (w2 << 1);
                float* op = out + nb * 512 + col;
                op[0]            = acc[mi][ni][0] + bv;
                op[512]          = acc[mi][ni][1] + bv;
                op[64 * 512]     = acc[mi][ni][2] + bv;
                op[65 * 512]     = acc[mi][ni][3] + bv;
            }
    }
}

// ---------------- launch 4: lo-fi projection GEMM, un-permuting epilogue ----------------
__global__ __launch_bounds__(256, 2) void k_mmproj_lo(
        const unsigned short* __restrict__ aout,
        const unsigned short* __restrict__ lprojT,
        const float* __restrict__ l_proj_b,
        float* __restrict__ out) {
    __shared__ __align__(16) unsigned short As[128 * 32];
    __shared__ __align__(16) unsigned short Bs[128 * 32];
    const int bid = blockIdx.x;                  // 0..511, 512%8==0 -> bijective
    const int f = (bid & 7) * 64 + (bid >> 3);
    const size_t row0 = (size_t)(f >> 1) * 128;
    const int col0 = (f & 1) * 128;

    f32x4 acc[4][4] = {};
    mm_core(aout, lprojT, row0, col0, 256, As, Bs, acc);

    const int tid = threadIdx.x;
    const int wave = tid >> 6, lane = tid & 63;
    const int m16 = lane & 15, quad = lane >> 4;
    const int wr = wave >> 1, wc = wave & 1;

#pragma unroll
    for (int mi = 0; mi < 4; mi++)
#pragma unroll
        for (int ni = 0; ni < 4; ni++) {
            const int col = col0 + wc * 64 + ni * 16 + m16;
            const float bv = l_proj_b[col];
            const size_t mb = row0 + wr * 64 + mi * 16 + quad * 4;
            const int widx = (int)(mb >> 2);
            const int b = widx >> 10, rem = widx & 1023;
            const int h2 = rem >> 5, w2 = rem & 31;
            const size_t nb = ((size_t)b << 12) + (h2 << 7) + (w2 << 1);
            float* op = out + nb * 512 + 256 + col;
            op[0]            = acc[mi][ni][0] + bv;
            op[512]          = acc[mi][ni][1] + bv;
            op[64 * 512]     = acc[mi][ni][2] + bv;
            op[65 * 512]     = acc[mi][ni][3] + bv;
        }
}

// ---------------- launcher ----------------

extern "C" void kernel_launch(void* const* d_in, const int* in_sizes, int n_in,
                              void* d_out, int out_size, void* d_ws, size_t ws_size,
                              hipStream_t stream) {
    (void)in_sizes; (void)n_in; (void)out_size; (void)ws_size;
    const float* x        = (const float*)d_in[0];
    const float* l_q_w    = (const float*)d_in[2];
    const float* l_kv_w   = (const float*)d_in[3];
    const float* l_proj_w = (const float*)d_in[4];
    const float* l_proj_b = (const float*)d_in[5];
    const float* h_qkv_w  = (const float*)d_in[6];
    const float* h_proj_w = (const float*)d_in[7];
    const float* h_proj_b = (const float*)d_in[8];
    float* out = (float*)d_out;

    char* ws = (char*)d_ws;
    unsigned short* xb     = (unsigned short*)(ws);             // 33.5MB, dead after mm512
    unsigned short* aout   = (unsigned short*)(ws);             // 16.8MB, overlays xb
    unsigned short* dbuf   = (unsigned short*)(ws + 33554432);  // 16.8MB
    unsigned short* qbuf   = (unsigned short*)(ws + 50331648);  // 16.8MB
    unsigned short* kbuf   = (unsigned short*)(ws + 67108864);  // 4.2MB
    unsigned short* vT     = (unsigned short*)(ws + 71303168);  // 4.2MB
    unsigned short* xpb    = (unsigned short*)(ws + 75497472);  // 8.4MB
    unsigned short* wcatT  = (unsigned short*)(ws + 83886080);
    unsigned short* lkvT   = (unsigned short*)(ws + 84410368);
    unsigned short* hprojT = (unsigned short*)(ws + 84934656);
    unsigned short* lprojT = (unsigned short*)(ws + 85065728);
    // total ws requirement: 85,196,800 B (same as prior rounds)

    // fused cast+pool (2048) + weight transpose (2560)
    k_prep<<<4608, 256, 0, stream>>>(x, h_qkv_w, l_q_w, l_kv_w, h_proj_w, l_proj_w,
                                     xb, xpb, wcatT, lkvT, hprojT, lprojT);
    // gemm1 (1024 blocks) + kv-gemm (256 blocks), fused hifi / V^T epilogues, XCD swizzle
    k_mm512<<<1280, 256, 0, stream>>>(xb, xpb, wcatT, lkvT, dbuf, qbuf, kbuf, vT);
    // attention (0..511) co-resident with hi-proj (512..1023): 4 blocks/CU
    // (aout overlays xb -- xb dead after mm512)
    k_attn_hiproj<<<1024, 256, 0, stream>>>(qbuf, kbuf, vT, aout, dbuf, hprojT, h_proj_b, out);
    // lo-proj + bias + un-permute into out
    k_mmproj_lo<<<512, 256, 0, stream>>>(aout, lprojT, l_proj_b, out);
}